// Round 4
// baseline (4919.278 us; speedup 1.0000x reference)
//
#include <hip/hip_runtime.h>

#define DEV __device__ __forceinline__

constexpr int NB  = 32;
constexpr int LXc = 256;
constexpr int LYc = 128;
constexpr int Dc  = 768;
constexpr int NH  = 12;
constexpr int FFc = 3072;

typedef unsigned short u16;
typedef float f32x4 __attribute__((ext_vector_type(4)));
typedef short s16x8 __attribute__((ext_vector_type(8)));

DEV u16 f2bf(float f) {
  unsigned u = __float_as_uint(f);
  u += 0x7FFFu + ((u >> 16) & 1u);
  return (u16)(u >> 16);
}
DEV float bf2f(u16 w) { return __uint_as_float(((unsigned)w) << 16); }
DEV float ldf(const void* p, long long i, int isbf) {
  return isbf ? bf2f(((const u16*)p)[i]) : ((const float*)p)[i];
}

DEV void gload16(const void* g, void* l) {
  __builtin_amdgcn_global_load_lds(
      (const __attribute__((address_space(1))) void*)g,
      (__attribute__((address_space(3))) void*)l, 16, 0, 0);
}
DEV void barx() {
  asm volatile("" ::: "memory");
  __builtin_amdgcn_s_barrier();
  asm volatile("" ::: "memory");
}

// ---------------- dtype detection ----------------
__global__ void k_detect(const u16* y, int* flag) {
  if (threadIdx.x == 0) {
    int cnt = 0;
    for (int i = 0; i < 256; ++i) {
      u16 w = y[i];
      int e = (w >> 7) & 0xFF;
      if (e == 0 || (e >= 112 && e <= 140)) cnt++;
    }
    *flag = (cnt >= 200) ? 1 : 0;
  }
}

__global__ void k_ingest2(const void* src, float* dst, u16* dstb, long long n, const int* flag) {
  int isbf = *flag;
  long long i = (long long)blockIdx.x * blockDim.x + threadIdx.x;
  long long st = (long long)gridDim.x * blockDim.x;
  for (; i < n; i += st) { float v = ldf(src, i, isbf); dst[i] = v; dstb[i] = f2bf(v); }
}

__global__ void k_cvt(const void* src, float* dst, long long n, const int* flag) {
  int isbf = *flag;
  long long i = (long long)blockIdx.x * blockDim.x + threadIdx.x;
  long long st = (long long)gridDim.x * blockDim.x;
  for (; i < n; i += st) dst[i] = ldf(src, i, isbf);
}

__global__ void k_emit(const float* ybuf, const float* xbuf, void* out,
                       const int* flag, long long ny, long long nt) {
  int isbf = *flag;
  long long i = (long long)blockIdx.x * blockDim.x + threadIdx.x;
  long long st = (long long)gridDim.x * blockDim.x;
  for (; i < nt; i += st) {
    float v = (i < ny) ? ybuf[i] : xbuf[i - ny];
    if (isbf) ((u16*)out)[i] = f2bf(v);
    else      ((float*)out)[i] = v;
  }
}

// ---------------- weight transpose+convert: [R][C] raw -> [C][R] bf16 ----------------
__global__ __launch_bounds__(256) void k_wt(const void* src, u16* dst, int R, int C, const int* flag) {
  int isbf = *flag;
  __shared__ u16 t[32][33];
  long long base = (long long)blockIdx.z * R * C;
  int c0 = blockIdx.x * 32, r0 = blockIdx.y * 32;
  int tx = threadIdx.x & 31, ty = threadIdx.x >> 5;
#pragma unroll
  for (int k = 0; k < 4; ++k) {
    int r = r0 + ty + k * 8;
    t[ty + k * 8][tx] = f2bf(ldf(src, base + (long long)r * C + (c0 + tx), isbf));
  }
  __syncthreads();
#pragma unroll
  for (int k = 0; k < 4; ++k) {
    int c = c0 + ty + k * 8;
    dst[base + (long long)c * R + (r0 + tx)] = t[tx][ty + k * 8];
  }
}

// ---------------- bbox cosine-sim + softmax (bf16 out) ----------------
__global__ __launch_bounds__(256) void k_bboxsim(const void* bbox, const int* flag, u16* sim) {
  int isbf = *flag;
  int b = blockIdx.x >> 8, i = blockIdx.x & 255;
  int j = threadIdx.x;
  long long base = (long long)b * LXc * 4;
  float a[4], c[4];
#pragma unroll
  for (int t = 0; t < 4; ++t) {
    a[t] = ldf(bbox, base + (long long)i * 4 + t, isbf);
    c[t] = ldf(bbox, base + (long long)j * 4 + t, isbf);
  }
  float dot = a[0]*c[0] + a[1]*c[1] + a[2]*c[2] + a[3]*c[3];
  float na  = sqrtf(a[0]*a[0] + a[1]*a[1] + a[2]*a[2] + a[3]*a[3]);
  float ncn = sqrtf(c[0]*c[0] + c[1]*c[1] + c[2]*c[2] + c[3]*c[3]);
  float v = dot / (na * ncn);
  __shared__ float r1[4], r2[4];
  float m = v;
  for (int o = 32; o; o >>= 1) m = fmaxf(m, __shfl_xor(m, o));
  if ((threadIdx.x & 63) == 0) r1[threadIdx.x >> 6] = m;
  __syncthreads();
  m = fmaxf(fmaxf(r1[0], r1[1]), fmaxf(r1[2], r1[3]));
  float e = __expf(v - m);
  float s = e;
  for (int o = 32; o; o >>= 1) s += __shfl_xor(s, o);
  if ((threadIdx.x & 63) == 0) r2[threadIdx.x >> 6] = s;
  __syncthreads();
  s = r2[0] + r2[1] + r2[2] + r2[3];
  sim[((long long)b * LXc + i) * LXc + j] = f2bf(e / s);
}

// ---------------- in-place bf16 row softmax ----------------
__global__ __launch_bounds__(256) void k_softmax2(u16* S, int Lk, long long nrows) {
  long long row = (long long)blockIdx.x * 4 + (threadIdx.x >> 6);
  int lane = threadIdx.x & 63;
  if (row >= nrows) return;
  u16* r = S + row * Lk;
  int nv = Lk >> 6;
  float v[4];
  float mx = -3.0e38f;
  for (int i = 0; i < nv; ++i) { v[i] = bf2f(r[i * 64 + lane]); mx = fmaxf(mx, v[i]); }
  for (int o = 32; o; o >>= 1) mx = fmaxf(mx, __shfl_xor(mx, o));
  float s = 0.f;
  for (int i = 0; i < nv; ++i) { v[i] = __expf(v[i] - mx); s += v[i]; }
  for (int o = 32; o; o >>= 1) s += __shfl_xor(s, o);
  float inv = 1.0f / s;
  for (int i = 0; i < nv; ++i) r[i * 64 + lane] = f2bf(v[i] * inv);
}

// ---------------- residual + layernorm -> f32 cur + bf16 mirror ----------------
__global__ __launch_bounds__(256) void k_lnres2(float* cur, u16* curb, const float* delta,
                                                const void* g, long long gOff,
                                                const void* bb, long long bOff,
                                                const int* flag) {
  int isbf = *flag;
  long long row = blockIdx.x;
  float* xr = cur + row * Dc;
  const float* dr = delta + row * Dc;
  int t = threadIdx.x;
  float v[3];
  float s = 0.f;
#pragma unroll
  for (int i = 0; i < 3; ++i) { int c = t + i * 256; v[i] = xr[c] + dr[c]; s += v[i]; }
  __shared__ float r1[4], r2[4];
  for (int o = 32; o; o >>= 1) s += __shfl_xor(s, o);
  if ((t & 63) == 0) r1[t >> 6] = s;
  __syncthreads();
  float mean = (r1[0] + r1[1] + r1[2] + r1[3]) * (1.0f / 768.0f);
  float s2 = 0.f;
#pragma unroll
  for (int i = 0; i < 3; ++i) { float d = v[i] - mean; s2 += d * d; }
  for (int o = 32; o; o >>= 1) s2 += __shfl_xor(s2, o);
  if ((t & 63) == 0) r2[t >> 6] = s2;
  __syncthreads();
  float var = (r2[0] + r2[1] + r2[2] + r2[3]) * (1.0f / 768.0f);
  float rstd = rsqrtf(var + 1e-6f);
#pragma unroll
  for (int i = 0; i < 3; ++i) {
    int c = t + i * 256;
    float o = ldf(g, gOff + c, isbf) * (v[i] - mean) * rstd + ldf(bb, bOff + c, isbf);
    xr[c] = o;
    curb[row * Dc + c] = f2bf(o);
  }
}

// ---------------- GEMM param block ----------------
struct G2 {
  const u16* A; long long lda, sAb, sAh;
  const u16* W; long long ldw, sWb, sWh;
  const float* bias; long long bOff;
  void* C; long long ldc, sCb, sCh;
  void* Ck; void* Cv; int vSeg;
  int Hdim; float scale; int relu; int Lseq;
};

// ---------------- 128x128 2-phase MFMA GEMM (batched / small grids) ----------------
template<int BM, int BN, int MODE>
__global__ __launch_bounds__(256, 2) void gemm2(G2 p, int M, int N, int K) {
  constexpr int BK = 64;
  __shared__ __align__(16) u16 Al[BM * BK];
  __shared__ __align__(16) u16 Bl[BN * BK];
  const int tid = threadIdx.x, wid = tid >> 6, lane = tid & 63;
  const int z = blockIdx.z, zb = z / p.Hdim, zh = z % p.Hdim;
  int bx = blockIdx.x, by = blockIdx.y;
  if (gridDim.z == 1) {
    int gx = gridDim.x, nwg = gx * gridDim.y;
    int orig = by * gx + bx;
    int q = nwg >> 3, r = nwg & 7, xcd = orig & 7, lin = orig >> 3;
    int wg = (xcd < r ? xcd * (q + 1) : r * (q + 1) + (xcd - r) * q) + lin;
    bx = wg % gx; by = wg / gx;
  }
  const u16* A = p.A + (long long)zb * p.sAb + (long long)zh * p.sAh;
  const u16* W = p.W + (long long)zb * p.sWb + (long long)zh * p.sWh;
  const int m0 = by * BM, n0 = bx * BN;
  const int wr = wid >> 1, wc = wid & 1;
  constexpr int FM = BM / 32, FN = BN / 32;
  f32x4 acc[FM][FN] = {};
  const int lr = lane >> 3;
  const int lo = (lane & 7) * 16;

  for (int k0 = 0; k0 < K; k0 += BK) {
#pragma unroll
    for (int i = 0; i < BM / 32; ++i) {
      int chunk = wid * (BM / 32) + i;
      int row = chunk * 8 + lr;
      gload16((const char*)(A + (long long)(m0 + row) * p.lda + k0) + lo,
              (char*)Al + chunk * 1024);
    }
#pragma unroll
    for (int i = 0; i < BN / 32; ++i) {
      int chunk = wid * (BN / 32) + i;
      int row = chunk * 8 + lr;
      gload16((const char*)(W + (long long)(n0 + row) * p.ldw + k0) + lo,
              (char*)Bl + chunk * 1024);
    }
    __syncthreads();
#pragma unroll
    for (int ks = 0; ks < 2; ++ks) {
      s16x8 af[FM], bfr[FN];
      const int kc = ks * 32 + (lane >> 4) * 8;
      const int rl = lane & 15;
#pragma unroll
      for (int i = 0; i < FM; ++i) af[i]  = *(const s16x8*)&Al[(wr * (BM / 2) + i * 16 + rl) * BK + kc];
#pragma unroll
      for (int j = 0; j < FN; ++j) bfr[j] = *(const s16x8*)&Bl[(wc * (BN / 2) + j * 16 + rl) * BK + kc];
#pragma unroll
      for (int i = 0; i < FM; ++i)
#pragma unroll
        for (int j = 0; j < FN; ++j)
          acc[i][j] = __builtin_amdgcn_mfma_f32_16x16x32_bf16(af[i], bfr[j], acc[i][j], 0, 0, 0);
    }
    __syncthreads();
  }

  const int seg = (MODE == 4) ? (n0 / 768) : 0;
#pragma unroll
  for (int j = 0; j < FN; ++j) {
    int col = n0 + wc * (BN / 2) + j * 16 + (lane & 15);
    float bv = p.bias ? p.bias[p.bOff + col] : 0.f;
#pragma unroll
    for (int i = 0; i < FM; ++i) {
      int row0 = m0 + wr * (BM / 2) + i * 16 + (lane >> 4) * 4;
      if (MODE == 0) {
        u16* C = (u16*)p.C + (long long)zb * p.sCb + (long long)zh * p.sCh;
#pragma unroll
        for (int e = 0; e < 4; ++e) {
          float v = acc[i][j][e] * p.scale + bv;
          if (p.relu) v = fmaxf(v, 0.f);
          C[(long long)(row0 + e) * p.ldc + col] = f2bf(v);
        }
      } else if (MODE == 1) {
        float* C = (float*)p.C + (long long)zb * p.sCb + (long long)zh * p.sCh;
#pragma unroll
        for (int e = 0; e < 4; ++e)
          C[(long long)(row0 + e) * p.ldc + col] = acc[i][j][e] * p.scale + bv;
      } else if (MODE == 2) {
        u16* C = (u16*)p.C;
        int b = row0 / p.Lseq, l = row0 % p.Lseq;
        union { u16 u[4]; uint2 d; } pk;
#pragma unroll
        for (int e = 0; e < 4; ++e) pk.u[e] = f2bf(acc[i][j][e] * p.scale + bv);
        *(uint2*)&C[((long long)b * Dc + col) * p.Lseq + l] = pk.d;
      } else if (MODE == 3) {
        u16* C = (u16*)p.C + (long long)zb * p.sCb + (long long)zh * p.sCh;
        union { u16 u[4]; uint2 d; } pk;
#pragma unroll
        for (int e = 0; e < 4; ++e) pk.u[e] = f2bf(acc[i][j][e] * p.scale + bv);
        *(uint2*)&C[(long long)col * p.ldc + row0] = pk.d;
      } else {  // MODE 4
        u16* outp = seg == 0 ? (u16*)p.C : (seg == 1 ? (u16*)p.Ck : (u16*)p.Cv);
        int c = col - seg * 768;
        if (seg == p.vSeg) {
          int b = row0 / p.Lseq, l = row0 % p.Lseq;
          union { u16 u[4]; uint2 d; } pk;
#pragma unroll
          for (int e = 0; e < 4; ++e) pk.u[e] = f2bf(acc[i][j][e] + bv);
          *(uint2*)&outp[((long long)b * Dc + c) * p.Lseq + l] = pk.d;
        } else {
#pragma unroll
          for (int e = 0; e < 4; ++e)
            outp[(long long)(row0 + e) * 768 + c] = f2bf(acc[i][j][e] + bv);
        }
      }
    }
  }
}

// ---------------- 256x256 deep-pipelined MFMA GEMM (T2+T3+T4+T5) ----------------
// 512 threads = 8 waves (2M x 4N); per-wave output 128x64; BK=64.
// LDS 128 KiB: 2 buffers x (A 32K + B 32K). Staging for tile t+2 issued in a
// burst at the tile switch into the just-freed buffer; switch waits vmcnt(8)
// (8 loads stay in flight, never drains to 0 mid-loop).
// T2 swizzle: LDS slot s holds global 16B-slot s ^ (row&7); gload source is
// pre-swizzled per-lane; ds_read applies the same XOR.
template<int MODE>
__global__ __launch_bounds__(512, 2) void gemm8(G2 p, int M, int N, int K) {
  extern __shared__ __align__(16) char sm[];
  const int tid = threadIdx.x, wid = tid >> 6, lane = tid & 63;
  const int wm = wid >> 2, wn = wid & 3;
  int bx = blockIdx.x, by = blockIdx.y;
  {
    int gx = gridDim.x, nwg = gx * gridDim.y;
    int orig = by * gx + bx;
    int q = nwg >> 3, r = nwg & 7, xcd = orig & 7, lin = orig >> 3;
    int wg = (xcd < r ? xcd * (q + 1) : r * (q + 1) + (xcd - r) * q) + lin;
    bx = wg % gx; by = wg / gx;
  }
  const int m0 = by * 256, n0 = bx * 256;
  const u16* Ag = p.A;
  const u16* Wg = p.W;
  const long long lda = p.lda, ldw = p.ldw;
  const int NT = K >> 6;

  // staging lane constants (inverse swizzle on the global source)
  const int srow = lane >> 3;                    // row within 8-row chunk
  const int scol = ((lane & 7) ^ srow) << 3;     // element col (16B slot swizzled)
  // read lane constants
  const int rl = lane & 15;
  const int lx = lane & 7;
  const int sx = lane >> 4;
  const int slotb0 = ((sx + 0) ^ lx) << 4;       // byte off, ks=0
  const int slotb1 = ((sx + 4) ^ lx) << 4;       // byte off, ks=1

  auto stage = [&](int t, int bufbase) {
    long long k0 = (long long)t << 6;
#pragma unroll
    for (int g = 0; g < 4; ++g) {
      int chunk = g * 8 + wid;
      gload16(Ag + (long long)(m0 + chunk * 8 + srow) * lda + k0 + scol,
              sm + bufbase + chunk * 1024);
    }
#pragma unroll
    for (int g = 0; g < 4; ++g) {
      int chunk = g * 8 + wid;
      gload16(Wg + (long long)(n0 + chunk * 8 + srow) * ldw + k0 + scol,
              sm + bufbase + 32768 + chunk * 1024);
    }
  };

  f32x4 acc[8][4] = {};

  stage(0, 0);
  stage(1, 65536);
  asm volatile("s_waitcnt vmcnt(8)" ::: "memory");
  __builtin_amdgcn_s_barrier();
  asm volatile("" ::: "memory");

  for (int t = 0; t < NT; ++t) {
    const int bb = (t & 1) << 16;
    const char* aB = sm + bb;
    const char* bB = sm + bb + 32768;
    s16x8 ar[4][2], br[2][2];

    auto ldA = [&](int h) {
      const int rbase = wm * 128 + h * 64 + rl;
#pragma unroll
      for (int i = 0; i < 4; ++i) {
        ar[i][0] = *(const s16x8*)(aB + (rbase + i * 16) * 128 + slotb0);
        ar[i][1] = *(const s16x8*)(aB + (rbase + i * 16) * 128 + slotb1);
      }
    };
    auto ldB = [&](int c) {
      const int rbase = wn * 64 + c * 32 + rl;
#pragma unroll
      for (int j = 0; j < 2; ++j) {
        br[j][0] = *(const s16x8*)(bB + (rbase + j * 16) * 128 + slotb0);
        br[j][1] = *(const s16x8*)(bB + (rbase + j * 16) * 128 + slotb1);
      }
    };
    auto qmm = [&](int ih, int jc) {
      __builtin_amdgcn_s_setprio(1);
#pragma unroll
      for (int ks = 0; ks < 2; ++ks)
#pragma unroll
        for (int i = 0; i < 4; ++i)
#pragma unroll
          for (int j = 0; j < 2; ++j)
            acc[ih * 4 + i][jc * 2 + j] = __builtin_amdgcn_mfma_f32_16x16x32_bf16(
                ar[i][ks], br[j][ks], acc[ih * 4 + i][jc * 2 + j], 0, 0, 0);
      __builtin_amdgcn_s_setprio(0);
      barx();
    };

    ldA(0); ldB(0); qmm(0, 0);   // q0: rows 0-63,  cols 0-31
    ldB(1);         qmm(0, 1);   // q1: rows 0-63,  cols 32-63
    ldA(1);         qmm(1, 1);   // q2: rows 64-127, cols 32-63
    ldB(0);         qmm(1, 0);   // q3: rows 64-127, cols 0-31
    // after q3's barrier nobody reads buffer bb anymore -> refill it
    if (t + 2 < NT) {
      stage(t + 2, bb);
      asm volatile("s_waitcnt vmcnt(8)" ::: "memory");   // tile t+1 landed
    } else if (t + 1 < NT) {
      asm volatile("s_waitcnt vmcnt(0)" ::: "memory");
    }
    if (t + 1 < NT) {
      __builtin_amdgcn_s_barrier();
      asm volatile("" ::: "memory");
    }
  }

  const int seg = (MODE == 4) ? (n0 / 768) : 0;
#pragma unroll
  for (int j = 0; j < 4; ++j) {
    int col = n0 + wn * 64 + j * 16 + (lane & 15);
    float bv = p.bias ? p.bias[p.bOff + col] : 0.f;
#pragma unroll
    for (int i = 0; i < 8; ++i) {
      int row0 = m0 + wm * 128 + i * 16 + (lane >> 4) * 4;
      if (MODE == 0) {
        u16* C = (u16*)p.C;
#pragma unroll
        for (int e = 0; e < 4; ++e) {
          float v = acc[i][j][e] * p.scale + bv;
          if (p.relu) v = fmaxf(v, 0.f);
          C[(long long)(row0 + e) * p.ldc + col] = f2bf(v);
        }
      } else if (MODE == 1) {
        float* C = (float*)p.C;
#pragma unroll
        for (int e = 0; e < 4; ++e)
          C[(long long)(row0 + e) * p.ldc + col] = acc[i][j][e] * p.scale + bv;
      } else {  // MODE 4
        u16* outp = seg == 0 ? (u16*)p.C : (seg == 1 ? (u16*)p.Ck : (u16*)p.Cv);
        int c = col - seg * 768;
        if (seg == p.vSeg) {
          int b = row0 / p.Lseq, l = row0 % p.Lseq;
          union { u16 u[4]; uint2 d; } pk;
#pragma unroll
          for (int e = 0; e < 4; ++e) pk.u[e] = f2bf(acc[i][j][e] + bv);
          *(uint2*)&outp[((long long)b * Dc + c) * p.Lseq + l] = pk.d;
        } else {
#pragma unroll
          for (int e = 0; e < 4; ++e)
            outp[(long long)(row0 + e) * 768 + c] = f2bf(acc[i][j][e] + bv);
        }
      }
    }
  }
}

// ---------------- launch helpers ----------------
template<int BM, int BN, int MODE>
static void run_gemm(const G2& p, int M, int N, int K, int nz, hipStream_t st) {
  dim3 grid(N / BN, M / BM, nz);
  gemm2<BM, BN, MODE><<<grid, 256, 0, st>>>(p, M, N, K);
}

template<int MODE>
static void run_gemm8(const G2& p, int M, int N, int K, hipStream_t st) {
  dim3 grid(N / 256, M / 256, 1);
  gemm8<MODE><<<grid, 512, 131072, st>>>(p, M, N, K);
}

extern "C" void kernel_launch(void* const* d_in, const int* in_sizes, int n_in,
                              void* d_out, int out_size, void* d_ws, size_t ws_size,
                              hipStream_t stream) {
  // allow 128 KiB dynamic LDS on the big kernel (idempotent, capture-safe)
  (void)hipFuncSetAttribute((const void*)&gemm8<0>, hipFuncAttributeMaxDynamicSharedMemorySize, 131072);
  (void)hipFuncSetAttribute((const void*)&gemm8<1>, hipFuncAttributeMaxDynamicSharedMemorySize, 131072);
  (void)hipFuncSetAttribute((const void*)&gemm8<4>, hipFuncAttributeMaxDynamicSharedMemorySize, 131072);

  const void* y_in  = d_in[0];
  const void* x_in  = d_in[1];
  const void* bbox  = d_in[5];
  const void* enc_aw = d_in[6];  const void* enc_ab = d_in[7];
  const void* enc_w1 = d_in[8];  const void* enc_b1 = d_in[9];
  const void* enc_w2 = d_in[10]; const void* enc_b2 = d_in[11];
  const void* enc_lg = d_in[12]; const void* enc_lb = d_in[13];
  const void* dec_aw = d_in[14]; const void* dec_ab = d_in[15];
  const void* dec_w1 = d_in[16]; const void* dec_b1 = d_in[17];
  const void* dec_w2 = d_in[18]; const void* dec_b2 = d_in[19];
  const void* dec_lg = d_in[20]; const void* dec_lb = d_in[21];

  char* base = (char*)d_ws;
  size_t off = 0;
  auto alloc = [&](size_t bytes) { void* p = base + off; off = (off + bytes + 255) & ~(size_t)255; return p; };
  int*  flag = (int*)alloc(256);
  const long long DD = (long long)Dc * Dc;
  const long long DF = (long long)Dc * FFc;
  u16* WencA  = (u16*)alloc(24 * DD * 2);
  u16* WencW1 = (u16*)alloc(6 * DF * 2);
  u16* WencW2 = (u16*)alloc(6 * DF * 2);
  u16* WdecA  = (u16*)alloc(48 * DD * 2);
  u16* WdecW1 = (u16*)alloc(6 * DF * 2);
  u16* WdecW2 = (u16*)alloc(6 * DF * 2);
  float* BencA  = (float*)alloc(24 * Dc * 4);
  float* BencW1 = (float*)alloc(6 * FFc * 4);
  float* BencW2 = (float*)alloc(6 * Dc * 4);
  float* BdecA  = (float*)alloc(48 * Dc * 4);
  float* BdecW1 = (float*)alloc(6 * FFc * 4);
  float* BdecW2 = (float*)alloc(6 * Dc * 4);
  const long long NYt = (long long)NB * LYc * Dc;
  const long long NXt = (long long)NB * LXc * Dc;
  float* cur_y  = (float*)alloc(NYt * 4);
  float* cur_x  = (float*)alloc(NXt * 4);
  u16*   curb_y = (u16*)alloc(NYt * 2);
  u16*   curb_x = (u16*)alloc(NXt * 2);
  u16*   simb   = (u16*)alloc((long long)NB * LXc * LXc * 2);
  u16*   qbf    = (u16*)alloc(NXt * 2);
  u16*   kbf    = (u16*)alloc(NXt * 2);
  u16*   vT     = (u16*)alloc(NXt * 2);
  float* delta  = (float*)alloc(NXt * 4);
  u16*   aoT    = (u16*)alloc(NXt * 2);
  u16*   ao2    = (u16*)alloc(NXt * 2);
  u16*   scores = (u16*)alloc((long long)NB * NH * LXc * LXc * 2);

  k_detect<<<1, 64, 0, stream>>>((const u16*)y_in, flag);
  k_ingest2<<<1024, 256, 0, stream>>>(y_in, cur_y, curb_y, NYt, flag);
  k_ingest2<<<1024, 256, 0, stream>>>(x_in, cur_x, curb_x, NXt, flag);
  k_bboxsim<<<NB * LXc, 256, 0, stream>>>(bbox, flag, simb);
  k_wt<<<dim3(Dc/32, Dc/32, 24), 256, 0, stream>>>(enc_aw, WencA, Dc, Dc, flag);
  k_wt<<<dim3(FFc/32, Dc/32, 6), 256, 0, stream>>>(enc_w1, WencW1, Dc, FFc, flag);
  k_wt<<<dim3(Dc/32, FFc/32, 6), 256, 0, stream>>>(enc_w2, WencW2, FFc, Dc, flag);
  k_wt<<<dim3(Dc/32, Dc/32, 48), 256, 0, stream>>>(dec_aw, WdecA, Dc, Dc, flag);
  k_wt<<<dim3(FFc/32, Dc/32, 6), 256, 0, stream>>>(dec_w1, WdecW1, Dc, FFc, flag);
  k_wt<<<dim3(Dc/32, FFc/32, 6), 256, 0, stream>>>(dec_w2, WdecW2, FFc, Dc, flag);
  k_cvt<<<32, 256, 0, stream>>>(enc_ab, BencA, 24 * Dc, flag);
  k_cvt<<<32, 256, 0, stream>>>(enc_b1, BencW1, 6 * FFc, flag);
  k_cvt<<<32, 256, 0, stream>>>(enc_b2, BencW2, 6 * Dc, flag);
  k_cvt<<<32, 256, 0, stream>>>(dec_ab, BdecA, 48 * Dc, flag);
  k_cvt<<<32, 256, 0, stream>>>(dec_b1, BdecW1, 6 * FFc, flag);
  k_cvt<<<32, 256, 0, stream>>>(dec_b2, BdecW2, 6 * Dc, flag);

  // ---- helpers ----
  auto qkv8 = [&](const u16* A, int M, const u16* Wt, long long wOff,
                  const float* bias, long long bOff, int Lseq) {
    G2 p{}; p.A = A; p.lda = Dc; p.W = Wt + wOff; p.ldw = Dc;
    p.bias = bias; p.bOff = bOff;
    p.C = qbf; p.Ck = kbf; p.Cv = vT; p.vSeg = 2;
    p.Hdim = 1; p.scale = 1.f; p.Lseq = Lseq;
    run_gemm8<4>(p, M, 3 * Dc, Dc, stream);
  };
  auto kv8 = [&](const u16* A, int M, const u16* Wt, long long wOff,
                 const float* bias, long long bOff, int Lseq) {
    G2 p{}; p.A = A; p.lda = Dc; p.W = Wt + wOff; p.ldw = Dc;
    p.bias = bias; p.bOff = bOff;
    p.C = kbf; p.Ck = vT; p.vSeg = 1;
    p.Hdim = 1; p.scale = 1.f; p.Lseq = Lseq;
    run_gemm8<4>(p, M, 2 * Dc, Dc, stream);
  };
  auto b16_8 = [&](const u16* A, int M, const u16* Wt, long long wOff,
                   const float* bias, long long bOff, u16* C, int N, int K, int relu) {
    G2 p{}; p.A = A; p.lda = K; p.W = Wt + wOff; p.ldw = K;
    p.bias = bias; p.bOff = bOff; p.C = C; p.ldc = N;
    p.Hdim = 1; p.scale = 1.f; p.relu = relu;
    run_gemm8<0>(p, M, N, K, stream);
  };
  auto f32_8 = [&](const u16* A, int M, const u16* Wt, long long wOff,
                   const float* bias, long long bOff, float* C, int N, int K) {
    G2 p{}; p.A = A; p.lda = K; p.W = Wt + wOff; p.ldw = K;
    p.bias = bias; p.bOff = bOff; p.C = C; p.ldc = N;
    p.Hdim = 1; p.scale = 1.f;
    run_gemm8<1>(p, M, N, K, stream);
  };
  auto proj_f32 = [&](const u16* A, int M, const u16* Wt, long long wOff,
                      const float* bias, long long bOff, float* C, int N, int K) {
    G2 p{}; p.A = A; p.lda = K; p.W = Wt + wOff; p.ldw = K;
    p.bias = bias; p.bOff = bOff; p.C = C; p.ldc = N;
    p.Hdim = 1; p.scale = 1.f;
    run_gemm<128, 128, 1>(p, M, N, K, 1, stream);
  };
  auto proj_b16 = [&](const u16* A, int M, const u16* Wt, long long wOff,
                      const float* bias, long long bOff, u16* C, int N, int K, int relu) {
    G2 p{}; p.A = A; p.lda = K; p.W = Wt + wOff; p.ldw = K;
    p.bias = bias; p.bOff = bOff; p.C = C; p.ldc = N;
    p.Hdim = 1; p.scale = 1.f; p.relu = relu;
    run_gemm<128, 128, 0>(p, M, N, K, 1, stream);
  };
  auto g_scores = [&](const u16* Q, int Lq, const u16* Kb, int Lk) {
    G2 p{}; p.A = Q; p.lda = Dc; p.sAb = (long long)Lq * Dc; p.sAh = 64;
    p.W = Kb; p.ldw = Dc; p.sWb = (long long)Lk * Dc; p.sWh = 64;
    p.C = scores; p.ldc = Lk; p.sCb = (long long)NH * Lq * Lk; p.sCh = (long long)Lq * Lk;
    p.Hdim = NH; p.scale = 0.125f;
    run_gemm<128, 128, 0>(p, Lq, Lk, 64, NB * NH, stream);
  };
  auto g_pv = [&](int Lq, int Lk, int dec) {
    G2 p{}; p.A = scores; p.lda = Lk; p.sAb = (long long)NH * Lq * Lk; p.sAh = (long long)Lq * Lk;
    p.W = vT; p.ldw = Lk; p.sWb = (long long)Dc * Lk; p.sWh = (long long)64 * Lk;
    p.Hdim = NH; p.scale = 1.f;
    if (dec) {
      p.C = aoT; p.ldc = LXc; p.sCb = (long long)Dc * LXc; p.sCh = (long long)64 * LXc;
      run_gemm<128, 64, 3>(p, Lq, 64, Lk, NB * NH, stream);
    } else {
      p.C = ao2; p.ldc = Dc; p.sCb = (long long)LYc * Dc; p.sCh = 64;
      run_gemm<128, 64, 0>(p, Lq, 64, Lk, NB * NH, stream);
    }
  };
  auto g_rel = [&]() {
    G2 p{}; p.A = simb; p.lda = LXc; p.sAb = (long long)LXc * LXc;
    p.W = aoT; p.ldw = LXc; p.sWb = (long long)Dc * LXc;
    p.C = ao2; p.ldc = Dc; p.sCb = (long long)LXc * Dc;
    p.Hdim = 1; p.scale = 1.f;
    run_gemm<128, 128, 0>(p, LXc, Dc, LXc, NB, stream);
  };

  // ---- encoder ----
  for (int i = 0; i < 6; ++i) {
    int M = NB * LYc;
    long long wo = (long long)i * 4 * DD, bo = (long long)i * 4 * Dc;
    qkv8(curb_y, M, WencA, wo, BencA, bo, LYc);
    g_scores(qbf, LYc, kbf, LYc);
    k_softmax2<<<(NB * NH * LYc) / 4, 256, 0, stream>>>(scores, LYc, (long long)NB * NH * LYc);
    g_pv(LYc, LYc, 0);
    proj_f32(ao2, M, WencA, wo + 3 * DD, BencA, bo + 3 * Dc, delta, Dc, Dc);
    k_lnres2<<<M, 256, 0, stream>>>(cur_y, curb_y, delta, enc_lg, (long long)(i*2+0)*Dc, enc_lb, (long long)(i*2+0)*Dc, flag);
    b16_8(curb_y, M, WencW1, (long long)i * DF, BencW1, (long long)i * FFc, scores, FFc, Dc, 1);
    proj_f32(scores, M, WencW2, (long long)i * DF, BencW2, (long long)i * Dc, delta, Dc, FFc);
    k_lnres2<<<M, 256, 0, stream>>>(cur_y, curb_y, delta, enc_lg, (long long)(i*2+1)*Dc, enc_lb, (long long)(i*2+1)*Dc, flag);
  }

  // ---- decoder ----
  for (int i = 0; i < 6; ++i) {
    int M = NB * LXc;
    for (int a = 0; a < 2; ++a) {
      long long wo = (long long)(i * 2 + a) * 4 * DD;
      long long bo = (long long)(i * 2 + a) * 4 * Dc;
      if (a == 0) {
        qkv8(curb_x, M, WdecA, wo, BdecA, bo, LXc);
      } else {
        b16_8(curb_x, M, WdecA, wo, BdecA, bo, qbf, Dc, Dc, 0);
        kv8(curb_y, NB * LYc, WdecA, wo + DD, BdecA, bo + Dc, LYc);
      }
      int Lk = a ? LYc : LXc;
      g_scores(qbf, LXc, kbf, Lk);
      k_softmax2<<<(NB * NH * LXc) / 4, 256, 0, stream>>>(scores, Lk, (long long)NB * NH * LXc);
      g_pv(LXc, Lk, 1);
      g_rel();
      f32_8(ao2, M, WdecA, wo + 3 * DD, BdecA, bo + 3 * Dc, delta, Dc, Dc);
      k_lnres2<<<M, 256, 0, stream>>>(cur_x, curb_x, delta, dec_lg, (long long)(i*3+a)*Dc, dec_lb, (long long)(i*3+a)*Dc, flag);
    }
    b16_8(curb_x, M, WdecW1, (long long)i * DF, BdecW1, (long long)i * FFc, scores, FFc, Dc, 1);
    f32_8(scores, M, WdecW2, (long long)i * DF, BdecW2, (long long)i * Dc, delta, Dc, FFc);
    k_lnres2<<<M, 256, 0, stream>>>(cur_x, curb_x, delta, dec_lg, (long long)(i*3+2)*Dc, dec_lb, (long long)(i*3+2)*Dc, flag);
  }

  k_emit<<<2048, 256, 0, stream>>>(cur_y, cur_x, d_out, flag, NYt, NYt + NXt);
}

// Round 5
// 4613.874 us; speedup vs baseline: 1.0662x; 1.0662x over previous
//
#include <hip/hip_runtime.h>

#define DEV __device__ __forceinline__

constexpr int NB  = 32;
constexpr int LXc = 256;
constexpr int LYc = 128;
constexpr int Dc  = 768;
constexpr int NH  = 12;
constexpr int FFc = 3072;

typedef unsigned short u16;
typedef float f32x4 __attribute__((ext_vector_type(4)));
typedef short s16x8 __attribute__((ext_vector_type(8)));

DEV u16 f2bf(float f) {
  unsigned u = __float_as_uint(f);
  u += 0x7FFFu + ((u >> 16) & 1u);
  return (u16)(u >> 16);
}
DEV float bf2f(u16 w) { return __uint_as_float(((unsigned)w) << 16); }
DEV float ldf(const void* p, long long i, int isbf) {
  return isbf ? bf2f(((const u16*)p)[i]) : ((const float*)p)[i];
}

DEV void gload16(const void* g, void* l) {
  __builtin_amdgcn_global_load_lds(
      (const __attribute__((address_space(1))) void*)g,
      (__attribute__((address_space(3))) void*)l, 16, 0, 0);
}
DEV void barx() {
  asm volatile("" ::: "memory");
  __builtin_amdgcn_s_barrier();
  asm volatile("" ::: "memory");
}

// ---------------- dtype detection ----------------
__global__ void k_detect(const u16* y, int* flag) {
  if (threadIdx.x == 0) {
    int cnt = 0;
    for (int i = 0; i < 256; ++i) {
      u16 w = y[i];
      int e = (w >> 7) & 0xFF;
      if (e == 0 || (e >= 112 && e <= 140)) cnt++;
    }
    *flag = (cnt >= 200) ? 1 : 0;
  }
}

__global__ void k_ingest2(const void* src, float* dst, u16* dstb, long long n, const int* flag) {
  int isbf = *flag;
  long long i = (long long)blockIdx.x * blockDim.x + threadIdx.x;
  long long st = (long long)gridDim.x * blockDim.x;
  for (; i < n; i += st) { float v = ldf(src, i, isbf); dst[i] = v; dstb[i] = f2bf(v); }
}

__global__ void k_cvt(const void* src, float* dst, long long n, const int* flag) {
  int isbf = *flag;
  long long i = (long long)blockIdx.x * blockDim.x + threadIdx.x;
  long long st = (long long)gridDim.x * blockDim.x;
  for (; i < n; i += st) dst[i] = ldf(src, i, isbf);
}

__global__ void k_emit(const float* ybuf, const float* xbuf, void* out,
                       const int* flag, long long ny, long long nt) {
  int isbf = *flag;
  long long i = (long long)blockIdx.x * blockDim.x + threadIdx.x;
  long long st = (long long)gridDim.x * blockDim.x;
  for (; i < nt; i += st) {
    float v = (i < ny) ? ybuf[i] : xbuf[i - ny];
    if (isbf) ((u16*)out)[i] = f2bf(v);
    else      ((float*)out)[i] = v;
  }
}

// ---------------- weight transpose+convert: [R][C] raw -> [C][R] bf16 ----------------
__global__ __launch_bounds__(256) void k_wt(const void* src, u16* dst, int R, int C, const int* flag) {
  int isbf = *flag;
  __shared__ u16 t[32][33];
  long long base = (long long)blockIdx.z * R * C;
  int c0 = blockIdx.x * 32, r0 = blockIdx.y * 32;
  int tx = threadIdx.x & 31, ty = threadIdx.x >> 5;
#pragma unroll
  for (int k = 0; k < 4; ++k) {
    int r = r0 + ty + k * 8;
    t[ty + k * 8][tx] = f2bf(ldf(src, base + (long long)r * C + (c0 + tx), isbf));
  }
  __syncthreads();
#pragma unroll
  for (int k = 0; k < 4; ++k) {
    int c = c0 + ty + k * 8;
    dst[base + (long long)c * R + (r0 + tx)] = t[tx][ty + k * 8];
  }
}

// ---------------- bbox cosine-sim + softmax (bf16 out) ----------------
__global__ __launch_bounds__(256) void k_bboxsim(const void* bbox, const int* flag, u16* sim) {
  int isbf = *flag;
  int b = blockIdx.x >> 8, i = blockIdx.x & 255;
  int j = threadIdx.x;
  long long base = (long long)b * LXc * 4;
  float a[4], c[4];
#pragma unroll
  for (int t = 0; t < 4; ++t) {
    a[t] = ldf(bbox, base + (long long)i * 4 + t, isbf);
    c[t] = ldf(bbox, base + (long long)j * 4 + t, isbf);
  }
  float dot = a[0]*c[0] + a[1]*c[1] + a[2]*c[2] + a[3]*c[3];
  float na  = sqrtf(a[0]*a[0] + a[1]*a[1] + a[2]*a[2] + a[3]*a[3]);
  float ncn = sqrtf(c[0]*c[0] + c[1]*c[1] + c[2]*c[2] + c[3]*c[3]);
  float v = dot / (na * ncn);
  __shared__ float r1[4], r2[4];
  float m = v;
  for (int o = 32; o; o >>= 1) m = fmaxf(m, __shfl_xor(m, o));
  if ((threadIdx.x & 63) == 0) r1[threadIdx.x >> 6] = m;
  __syncthreads();
  m = fmaxf(fmaxf(r1[0], r1[1]), fmaxf(r1[2], r1[3]));
  float e = __expf(v - m);
  float s = e;
  for (int o = 32; o; o >>= 1) s += __shfl_xor(s, o);
  if ((threadIdx.x & 63) == 0) r2[threadIdx.x >> 6] = s;
  __syncthreads();
  s = r2[0] + r2[1] + r2[2] + r2[3];
  sim[((long long)b * LXc + i) * LXc + j] = f2bf(e / s);
}

// ---------------- in-place bf16 row softmax ----------------
__global__ __launch_bounds__(256) void k_softmax2(u16* S, int Lk, long long nrows) {
  long long row = (long long)blockIdx.x * 4 + (threadIdx.x >> 6);
  int lane = threadIdx.x & 63;
  if (row >= nrows) return;
  u16* r = S + row * Lk;
  int nv = Lk >> 6;
  float v[4];
  float mx = -3.0e38f;
  for (int i = 0; i < nv; ++i) { v[i] = bf2f(r[i * 64 + lane]); mx = fmaxf(mx, v[i]); }
  for (int o = 32; o; o >>= 1) mx = fmaxf(mx, __shfl_xor(mx, o));
  float s = 0.f;
  for (int i = 0; i < nv; ++i) { v[i] = __expf(v[i] - mx); s += v[i]; }
  for (int o = 32; o; o >>= 1) s += __shfl_xor(s, o);
  float inv = 1.0f / s;
  for (int i = 0; i < nv; ++i) r[i * 64 + lane] = f2bf(v[i] * inv);
}

// ---------------- residual + layernorm -> f32 cur + bf16 mirror ----------------
__global__ __launch_bounds__(256) void k_lnres2(float* cur, u16* curb, const float* delta,
                                                const void* g, long long gOff,
                                                const void* bb, long long bOff,
                                                const int* flag) {
  int isbf = *flag;
  long long row = blockIdx.x;
  float* xr = cur + row * Dc;
  const float* dr = delta + row * Dc;
  int t = threadIdx.x;
  float v[3];
  float s = 0.f;
#pragma unroll
  for (int i = 0; i < 3; ++i) { int c = t + i * 256; v[i] = xr[c] + dr[c]; s += v[i]; }
  __shared__ float r1[4], r2[4];
  for (int o = 32; o; o >>= 1) s += __shfl_xor(s, o);
  if ((t & 63) == 0) r1[t >> 6] = s;
  __syncthreads();
  float mean = (r1[0] + r1[1] + r1[2] + r1[3]) * (1.0f / 768.0f);
  float s2 = 0.f;
#pragma unroll
  for (int i = 0; i < 3; ++i) { float d = v[i] - mean; s2 += d * d; }
  for (int o = 32; o; o >>= 1) s2 += __shfl_xor(s2, o);
  if ((t & 63) == 0) r2[t >> 6] = s2;
  __syncthreads();
  float var = (r2[0] + r2[1] + r2[2] + r2[3]) * (1.0f / 768.0f);
  float rstd = rsqrtf(var + 1e-6f);
#pragma unroll
  for (int i = 0; i < 3; ++i) {
    int c = t + i * 256;
    float o = ldf(g, gOff + c, isbf) * (v[i] - mean) * rstd + ldf(bb, bOff + c, isbf);
    xr[c] = o;
    curb[row * Dc + c] = f2bf(o);
  }
}

// ---------------- GEMM param block ----------------
struct G2 {
  const u16* A; long long lda, sAb, sAh;
  const u16* W; long long ldw, sWb, sWh;
  const float* bias; long long bOff;
  void* C; long long ldc, sCb, sCh;
  void* Ck; void* Cv; int vSeg;
  int Hdim; float scale; int relu; int Lseq;
};

// ---------------- 128x128 2-phase MFMA GEMM (batched / small grids) ----------------
template<int BM, int BN, int MODE>
__global__ __launch_bounds__(256, 2) void gemm2(G2 p, int M, int N, int K) {
  constexpr int BK = 64;
  __shared__ __align__(16) u16 Al[BM * BK];
  __shared__ __align__(16) u16 Bl[BN * BK];
  const int tid = threadIdx.x, wid = tid >> 6, lane = tid & 63;
  const int z = blockIdx.z, zb = z / p.Hdim, zh = z % p.Hdim;
  int bx = blockIdx.x, by = blockIdx.y;
  if (gridDim.z == 1) {
    int gx = gridDim.x, nwg = gx * gridDim.y;
    int orig = by * gx + bx;
    int q = nwg >> 3, r = nwg & 7, xcd = orig & 7, lin = orig >> 3;
    int wg = (xcd < r ? xcd * (q + 1) : r * (q + 1) + (xcd - r) * q) + lin;
    bx = wg % gx; by = wg / gx;
  }
  const u16* A = p.A + (long long)zb * p.sAb + (long long)zh * p.sAh;
  const u16* W = p.W + (long long)zb * p.sWb + (long long)zh * p.sWh;
  const int m0 = by * BM, n0 = bx * BN;
  const int wr = wid >> 1, wc = wid & 1;
  constexpr int FM = BM / 32, FN = BN / 32;
  f32x4 acc[FM][FN] = {};
  const int lr = lane >> 3;
  const int lo = (lane & 7) * 16;

  for (int k0 = 0; k0 < K; k0 += BK) {
#pragma unroll
    for (int i = 0; i < BM / 32; ++i) {
      int chunk = wid * (BM / 32) + i;
      int row = chunk * 8 + lr;
      gload16((const char*)(A + (long long)(m0 + row) * p.lda + k0) + lo,
              (char*)Al + chunk * 1024);
    }
#pragma unroll
    for (int i = 0; i < BN / 32; ++i) {
      int chunk = wid * (BN / 32) + i;
      int row = chunk * 8 + lr;
      gload16((const char*)(W + (long long)(n0 + row) * p.ldw + k0) + lo,
              (char*)Bl + chunk * 1024);
    }
    __syncthreads();
#pragma unroll
    for (int ks = 0; ks < 2; ++ks) {
      s16x8 af[FM], bfr[FN];
      const int kc = ks * 32 + (lane >> 4) * 8;
      const int rl = lane & 15;
#pragma unroll
      for (int i = 0; i < FM; ++i) af[i]  = *(const s16x8*)&Al[(wr * (BM / 2) + i * 16 + rl) * BK + kc];
#pragma unroll
      for (int j = 0; j < FN; ++j) bfr[j] = *(const s16x8*)&Bl[(wc * (BN / 2) + j * 16 + rl) * BK + kc];
#pragma unroll
      for (int i = 0; i < FM; ++i)
#pragma unroll
        for (int j = 0; j < FN; ++j)
          acc[i][j] = __builtin_amdgcn_mfma_f32_16x16x32_bf16(af[i], bfr[j], acc[i][j], 0, 0, 0);
    }
    __syncthreads();
  }

  const int seg = (MODE == 4) ? (n0 / 768) : 0;
#pragma unroll
  for (int j = 0; j < FN; ++j) {
    int col = n0 + wc * (BN / 2) + j * 16 + (lane & 15);
    float bv = p.bias ? p.bias[p.bOff + col] : 0.f;
#pragma unroll
    for (int i = 0; i < FM; ++i) {
      int row0 = m0 + wr * (BM / 2) + i * 16 + (lane >> 4) * 4;
      if (MODE == 0) {
        u16* C = (u16*)p.C + (long long)zb * p.sCb + (long long)zh * p.sCh;
#pragma unroll
        for (int e = 0; e < 4; ++e) {
          float v = acc[i][j][e] * p.scale + bv;
          if (p.relu) v = fmaxf(v, 0.f);
          C[(long long)(row0 + e) * p.ldc + col] = f2bf(v);
        }
      } else if (MODE == 1) {
        float* C = (float*)p.C + (long long)zb * p.sCb + (long long)zh * p.sCh;
#pragma unroll
        for (int e = 0; e < 4; ++e)
          C[(long long)(row0 + e) * p.ldc + col] = acc[i][j][e] * p.scale + bv;
      } else if (MODE == 2) {
        u16* C = (u16*)p.C;
        int b = row0 / p.Lseq, l = row0 % p.Lseq;
        union { u16 u[4]; uint2 d; } pk;
#pragma unroll
        for (int e = 0; e < 4; ++e) pk.u[e] = f2bf(acc[i][j][e] * p.scale + bv);
        *(uint2*)&C[((long long)b * Dc + col) * p.Lseq + l] = pk.d;
      } else if (MODE == 3) {
        u16* C = (u16*)p.C + (long long)zb * p.sCb + (long long)zh * p.sCh;
        union { u16 u[4]; uint2 d; } pk;
#pragma unroll
        for (int e = 0; e < 4; ++e) pk.u[e] = f2bf(acc[i][j][e] * p.scale + bv);
        *(uint2*)&C[(long long)col * p.ldc + row0] = pk.d;
      } else {  // MODE 4
        u16* outp = seg == 0 ? (u16*)p.C : (seg == 1 ? (u16*)p.Ck : (u16*)p.Cv);
        int c = col - seg * 768;
        if (seg == p.vSeg) {
          int b = row0 / p.Lseq, l = row0 % p.Lseq;
          union { u16 u[4]; uint2 d; } pk;
#pragma unroll
          for (int e = 0; e < 4; ++e) pk.u[e] = f2bf(acc[i][j][e] + bv);
          *(uint2*)&outp[((long long)b * Dc + c) * p.Lseq + l] = pk.d;
        } else {
#pragma unroll
          for (int e = 0; e < 4; ++e)
            outp[(long long)(row0 + e) * 768 + c] = f2bf(acc[i][j][e] + bv);
        }
      }
    }
  }
}

// ---------------- 256x256 8-phase-interleaved MFMA GEMM (T2+T3+T4+T5) ----------------
// 512 threads = 8 waves (2M x 4N); per-wave output 128x64; BK=64; 2x64KB LDS dbuf.
// Per K-tile, 4 phases: [ds_read next frags (+P0: burst-stage tile t+1 into freed
// buffer)] -> barrier -> setprio MFMA quadrant setprio -> barrier. One vmcnt(0)
// per tile at P3; its 8 loads are 3 phases (~1000cy) old -> wait is nearly free.
template<int MODE>
__global__ __launch_bounds__(512, 2) void gemm8(G2 p, int M, int N, int K) {
  extern __shared__ __align__(16) char sm[];
  const int tid = threadIdx.x, wid = tid >> 6, lane = tid & 63;
  const int wm = wid >> 2, wn = wid & 3;
  int bx = blockIdx.x, by = blockIdx.y;
  {
    int gx = gridDim.x, nwg = gx * gridDim.y;
    int orig = by * gx + bx;
    int q = nwg >> 3, r = nwg & 7, xcd = orig & 7, lin = orig >> 3;
    int wg = (xcd < r ? xcd * (q + 1) : r * (q + 1) + (xcd - r) * q) + lin;
    bx = wg % gx; by = wg / gx;
  }
  const int m0 = by * 256, n0 = bx * 256;
  const u16* Ag = p.A;
  const u16* Wg = p.W;
  const long long lda = p.lda, ldw = p.ldw;
  const int NT = K >> 6;

  const int srow = lane >> 3;                 // staging: row in 8-row chunk
  const int scol = ((lane & 7) ^ srow) << 3;  // inverse-swizzled global col
  const int rl = lane & 15;
  const int lx = lane & 7;
  const int sx = lane >> 4;
  const int slotb0 = ((sx + 0) ^ lx) << 4;    // swizzled byte off, ks=0
  const int slotb1 = ((sx + 4) ^ lx) << 4;    // swizzled byte off, ks=1

  auto stage = [&](int t, int bufbase) {
    long long k0 = (long long)t << 6;
#pragma unroll
    for (int g = 0; g < 4; ++g) {
      int chunk = g * 8 + wid;
      gload16(Ag + (long long)(m0 + chunk * 8 + srow) * lda + k0 + scol,
              sm + bufbase + chunk * 1024);
    }
#pragma unroll
    for (int g = 0; g < 4; ++g) {
      int chunk = g * 8 + wid;
      gload16(Wg + (long long)(n0 + chunk * 8 + srow) * ldw + k0 + scol,
              sm + bufbase + 32768 + chunk * 1024);
    }
  };

  f32x4 acc[8][4] = {};
  s16x8 ar[4][2], br0[2][2], br1[2][2];

  stage(0, 0);
  asm volatile("s_waitcnt vmcnt(0)" ::: "memory");
  barx();

  for (int t = 0; t < NT; ++t) {
    const int bb = (t & 1) << 16;
    const char* aB = sm + bb;
    const char* bBf = sm + bb + 32768;

    auto ldA = [&](int h) {
      const int rbase = wm * 128 + h * 64 + rl;
#pragma unroll
      for (int i = 0; i < 4; ++i) {
        ar[i][0] = *(const s16x8*)(aB + (rbase + i * 16) * 128 + slotb0);
        ar[i][1] = *(const s16x8*)(aB + (rbase + i * 16) * 128 + slotb1);
      }
    };
    auto ldB = [&](int c, s16x8 (&br)[2][2]) {
      const int rbase = wn * 64 + c * 32 + rl;
#pragma unroll
      for (int j = 0; j < 2; ++j) {
        br[j][0] = *(const s16x8*)(bBf + (rbase + j * 16) * 128 + slotb0);
        br[j][1] = *(const s16x8*)(bBf + (rbase + j * 16) * 128 + slotb1);
      }
    };
    auto mm = [&](int ih, int jc, const s16x8 (&br)[2][2]) {
      __builtin_amdgcn_s_setprio(1);
#pragma unroll
      for (int ks = 0; ks < 2; ++ks)
#pragma unroll
        for (int i = 0; i < 4; ++i)
#pragma unroll
          for (int j = 0; j < 2; ++j)
            acc[ih * 4 + i][jc * 2 + j] = __builtin_amdgcn_mfma_f32_16x16x32_bf16(
                ar[i][ks], br[j][ks], acc[ih * 4 + i][jc * 2 + j], 0, 0, 0);
      __builtin_amdgcn_s_setprio(0);
    };

    // P0: issue A-low + B-col0 reads, burst-stage next tile, then MFMA q0
    ldA(0); ldB(0, br0);
    if (t + 1 < NT) stage(t + 1, bb ^ 65536);
    barx();
    mm(0, 0, br0);
    barx();
    // P1: B-col1 reads, MFMA q1
    ldB(1, br1);
    barx();
    mm(0, 1, br1);
    barx();
    // P2: A-high reads, MFMA q2
    ldA(1);
    barx();
    mm(1, 1, br1);
    barx();
    // P3: no reads (br0 cached), MFMA q3, then tile-switch wait
    mm(1, 0, br0);
    if (t + 1 < NT) {
      asm volatile("s_waitcnt vmcnt(0)" ::: "memory");  // next tile landed (~3 phases old)
      barx();
    }
  }

  const int seg = (MODE == 4) ? (n0 / 768) : 0;
#pragma unroll
  for (int j = 0; j < 4; ++j) {
    int col = n0 + wn * 64 + j * 16 + (lane & 15);
    float bv = p.bias ? p.bias[p.bOff + col] : 0.f;
#pragma unroll
    for (int i = 0; i < 8; ++i) {
      int row0 = m0 + wm * 128 + i * 16 + (lane >> 4) * 4;
      if (MODE == 0) {
        u16* C = (u16*)p.C;
#pragma unroll
        for (int e = 0; e < 4; ++e) {
          float v = acc[i][j][e] * p.scale + bv;
          if (p.relu) v = fmaxf(v, 0.f);
          C[(long long)(row0 + e) * p.ldc + col] = f2bf(v);
        }
      } else if (MODE == 1) {
        float* C = (float*)p.C;
#pragma unroll
        for (int e = 0; e < 4; ++e)
          C[(long long)(row0 + e) * p.ldc + col] = acc[i][j][e] * p.scale + bv;
      } else {  // MODE 4
        u16* outp = seg == 0 ? (u16*)p.C : (seg == 1 ? (u16*)p.Ck : (u16*)p.Cv);
        int c = col - seg * 768;
        if (seg == p.vSeg) {
          int b = row0 / p.Lseq, l = row0 % p.Lseq;
          union { u16 u[4]; uint2 d; } pk;
#pragma unroll
          for (int e = 0; e < 4; ++e) pk.u[e] = f2bf(acc[i][j][e] + bv);
          *(uint2*)&outp[((long long)b * Dc + c) * p.Lseq + l] = pk.d;
        } else {
#pragma unroll
          for (int e = 0; e < 4; ++e)
            outp[(long long)(row0 + e) * 768 + c] = f2bf(acc[i][j][e] + bv);
        }
      }
    }
  }
}

// ---------------- launch helpers ----------------
template<int BM, int BN, int MODE>
static void run_gemm(const G2& p, int M, int N, int K, int nz, hipStream_t st) {
  dim3 grid(N / BN, M / BM, nz);
  gemm2<BM, BN, MODE><<<grid, 256, 0, st>>>(p, M, N, K);
}

template<int MODE>
static void run_gemm8(const G2& p, int M, int N, int K, hipStream_t st) {
  dim3 grid(N / 256, M / 256, 1);
  gemm8<MODE><<<grid, 512, 131072, st>>>(p, M, N, K);
}

extern "C" void kernel_launch(void* const* d_in, const int* in_sizes, int n_in,
                              void* d_out, int out_size, void* d_ws, size_t ws_size,
                              hipStream_t stream) {
  (void)hipFuncSetAttribute((const void*)&gemm8<0>, hipFuncAttributeMaxDynamicSharedMemorySize, 131072);
  (void)hipFuncSetAttribute((const void*)&gemm8<4>, hipFuncAttributeMaxDynamicSharedMemorySize, 131072);

  const void* y_in  = d_in[0];
  const void* x_in  = d_in[1];
  const void* bbox  = d_in[5];
  const void* enc_aw = d_in[6];  const void* enc_ab = d_in[7];
  const void* enc_w1 = d_in[8];  const void* enc_b1 = d_in[9];
  const void* enc_w2 = d_in[10]; const void* enc_b2 = d_in[11];
  const void* enc_lg = d_in[12]; const void* enc_lb = d_in[13];
  const void* dec_aw = d_in[14]; const void* dec_ab = d_in[15];
  const void* dec_w1 = d_in[16]; const void* dec_b1 = d_in[17];
  const void* dec_w2 = d_in[18]; const void* dec_b2 = d_in[19];
  const void* dec_lg = d_in[20]; const void* dec_lb = d_in[21];

  char* base = (char*)d_ws;
  size_t off = 0;
  auto alloc = [&](size_t bytes) { void* p = base + off; off = (off + bytes + 255) & ~(size_t)255; return p; };
  int*  flag = (int*)alloc(256);
  const long long DD = (long long)Dc * Dc;
  const long long DF = (long long)Dc * FFc;
  u16* WencA  = (u16*)alloc(24 * DD * 2);
  u16* WencW1 = (u16*)alloc(6 * DF * 2);
  u16* WencW2 = (u16*)alloc(6 * DF * 2);
  u16* WdecA  = (u16*)alloc(48 * DD * 2);
  u16* WdecW1 = (u16*)alloc(6 * DF * 2);
  u16* WdecW2 = (u16*)alloc(6 * DF * 2);
  float* BencA  = (float*)alloc(24 * Dc * 4);
  float* BencW1 = (float*)alloc(6 * FFc * 4);
  float* BencW2 = (float*)alloc(6 * Dc * 4);
  float* BdecA  = (float*)alloc(48 * Dc * 4);
  float* BdecW1 = (float*)alloc(6 * FFc * 4);
  float* BdecW2 = (float*)alloc(6 * Dc * 4);
  const long long NYt = (long long)NB * LYc * Dc;
  const long long NXt = (long long)NB * LXc * Dc;
  float* cur_y  = (float*)alloc(NYt * 4);
  float* cur_x  = (float*)alloc(NXt * 4);
  u16*   curb_y = (u16*)alloc(NYt * 2);
  u16*   curb_x = (u16*)alloc(NXt * 2);
  u16*   simb   = (u16*)alloc((long long)NB * LXc * LXc * 2);
  u16*   qbf    = (u16*)alloc(NXt * 2);
  u16*   kbf    = (u16*)alloc(NXt * 2);
  u16*   vT     = (u16*)alloc(NXt * 2);
  float* delta  = (float*)alloc(NXt * 4);
  u16*   aoT    = (u16*)alloc(NXt * 2);
  u16*   ao2    = (u16*)alloc(NXt * 2);
  u16*   scores = (u16*)alloc((long long)NB * NH * LXc * LXc * 2);

  k_detect<<<1, 64, 0, stream>>>((const u16*)y_in, flag);
  k_ingest2<<<1024, 256, 0, stream>>>(y_in, cur_y, curb_y, NYt, flag);
  k_ingest2<<<1024, 256, 0, stream>>>(x_in, cur_x, curb_x, NXt, flag);
  k_bboxsim<<<NB * LXc, 256, 0, stream>>>(bbox, flag, simb);
  k_wt<<<dim3(Dc/32, Dc/32, 24), 256, 0, stream>>>(enc_aw, WencA, Dc, Dc, flag);
  k_wt<<<dim3(FFc/32, Dc/32, 6), 256, 0, stream>>>(enc_w1, WencW1, Dc, FFc, flag);
  k_wt<<<dim3(Dc/32, FFc/32, 6), 256, 0, stream>>>(enc_w2, WencW2, FFc, Dc, flag);
  k_wt<<<dim3(Dc/32, Dc/32, 48), 256, 0, stream>>>(dec_aw, WdecA, Dc, Dc, flag);
  k_wt<<<dim3(FFc/32, Dc/32, 6), 256, 0, stream>>>(dec_w1, WdecW1, Dc, FFc, flag);
  k_wt<<<dim3(Dc/32, FFc/32, 6), 256, 0, stream>>>(dec_w2, WdecW2, FFc, Dc, flag);
  k_cvt<<<32, 256, 0, stream>>>(enc_ab, BencA, 24 * Dc, flag);
  k_cvt<<<32, 256, 0, stream>>>(enc_b1, BencW1, 6 * FFc, flag);
  k_cvt<<<32, 256, 0, stream>>>(enc_b2, BencW2, 6 * Dc, flag);
  k_cvt<<<32, 256, 0, stream>>>(dec_ab, BdecA, 48 * Dc, flag);
  k_cvt<<<32, 256, 0, stream>>>(dec_b1, BdecW1, 6 * FFc, flag);
  k_cvt<<<32, 256, 0, stream>>>(dec_b2, BdecW2, 6 * Dc, flag);

  // ---- helpers ----
  auto qkv8 = [&](const u16* A, int M, const u16* Wt, long long wOff,
                  const float* bias, long long bOff, int Lseq) {
    G2 p{}; p.A = A; p.lda = Dc; p.W = Wt + wOff; p.ldw = Dc;
    p.bias = bias; p.bOff = bOff;
    p.C = qbf; p.Ck = kbf; p.Cv = vT; p.vSeg = 2;
    p.Hdim = 1; p.scale = 1.f; p.Lseq = Lseq;
    run_gemm8<4>(p, M, 3 * Dc, Dc, stream);
  };
  auto proj_kv2 = [&](const u16* A, int M, const u16* Wt, long long wOff,
                      const float* bias, long long bOff, int Lseq) {
    G2 p{}; p.A = A; p.lda = Dc; p.W = Wt + wOff; p.ldw = Dc;
    p.bias = bias; p.bOff = bOff;
    p.C = kbf; p.Ck = vT; p.vSeg = 1;
    p.Hdim = 1; p.scale = 1.f; p.Lseq = Lseq;
    run_gemm<128, 128, 4>(p, M, 2 * Dc, Dc, 1, stream);
  };
  auto b16_8 = [&](const u16* A, int M, const u16* Wt, long long wOff,
                   const float* bias, long long bOff, u16* C, int N, int K, int relu) {
    G2 p{}; p.A = A; p.lda = K; p.W = Wt + wOff; p.ldw = K;
    p.bias = bias; p.bOff = bOff; p.C = C; p.ldc = N;
    p.Hdim = 1; p.scale = 1.f; p.relu = relu;
    run_gemm8<0>(p, M, N, K, stream);
  };
  auto proj_f32 = [&](const u16* A, int M, const u16* Wt, long long wOff,
                      const float* bias, long long bOff, float* C, int N, int K) {
    G2 p{}; p.A = A; p.lda = K; p.W = Wt + wOff; p.ldw = K;
    p.bias = bias; p.bOff = bOff; p.C = C; p.ldc = N;
    p.Hdim = 1; p.scale = 1.f;
    run_gemm<128, 128, 1>(p, M, N, K, 1, stream);
  };
  auto proj_b16 = [&](const u16* A, int M, const u16* Wt, long long wOff,
                      const float* bias, long long bOff, u16* C, int N, int K, int relu) {
    G2 p{}; p.A = A; p.lda = K; p.W = Wt + wOff; p.ldw = K;
    p.bias = bias; p.bOff = bOff; p.C = C; p.ldc = N;
    p.Hdim = 1; p.scale = 1.f; p.relu = relu;
    run_gemm<128, 128, 0>(p, M, N, K, 1, stream);
  };
  auto g_scores = [&](const u16* Q, int Lq, const u16* Kb, int Lk) {
    G2 p{}; p.A = Q; p.lda = Dc; p.sAb = (long long)Lq * Dc; p.sAh = 64;
    p.W = Kb; p.ldw = Dc; p.sWb = (long long)Lk * Dc; p.sWh = 64;
    p.C = scores; p.ldc = Lk; p.sCb = (long long)NH * Lq * Lk; p.sCh = (long long)Lq * Lk;
    p.Hdim = NH; p.scale = 0.125f;
    run_gemm<128, 128, 0>(p, Lq, Lk, 64, NB * NH, stream);
  };
  auto g_pv = [&](int Lq, int Lk, int dec) {
    G2 p{}; p.A = scores; p.lda = Lk; p.sAb = (long long)NH * Lq * Lk; p.sAh = (long long)Lq * Lk;
    p.W = vT; p.ldw = Lk; p.sWb = (long long)Dc * Lk; p.sWh = (long long)64 * Lk;
    p.Hdim = NH; p.scale = 1.f;
    if (dec) {
      p.C = aoT; p.ldc = LXc; p.sCb = (long long)Dc * LXc; p.sCh = (long long)64 * LXc;
      run_gemm<128, 64, 3>(p, Lq, 64, Lk, NB * NH, stream);
    } else {
      p.C = ao2; p.ldc = Dc; p.sCb = (long long)LYc * Dc; p.sCh = 64;
      run_gemm<128, 64, 0>(p, Lq, 64, Lk, NB * NH, stream);
    }
  };
  auto g_rel = [&]() {
    G2 p{}; p.A = simb; p.lda = LXc; p.sAb = (long long)LXc * LXc;
    p.W = aoT; p.ldw = LXc; p.sWb = (long long)Dc * LXc;
    p.C = ao2; p.ldc = Dc; p.sCb = (long long)LXc * Dc;
    p.Hdim = 1; p.scale = 1.f;
    run_gemm<128, 128, 0>(p, LXc, Dc, LXc, NB, stream);
  };

  // ---- encoder ----
  for (int i = 0; i < 6; ++i) {
    int M = NB * LYc;
    long long wo = (long long)i * 4 * DD, bo = (long long)i * 4 * Dc;
    qkv8(curb_y, M, WencA, wo, BencA, bo, LYc);
    g_scores(qbf, LYc, kbf, LYc);
    k_softmax2<<<(NB * NH * LYc) / 4, 256, 0, stream>>>(scores, LYc, (long long)NB * NH * LYc);
    g_pv(LYc, LYc, 0);
    proj_f32(ao2, M, WencA, wo + 3 * DD, BencA, bo + 3 * Dc, delta, Dc, Dc);
    k_lnres2<<<M, 256, 0, stream>>>(cur_y, curb_y, delta, enc_lg, (long long)(i*2+0)*Dc, enc_lb, (long long)(i*2+0)*Dc, flag);
    b16_8(curb_y, M, WencW1, (long long)i * DF, BencW1, (long long)i * FFc, scores, FFc, Dc, 1);
    proj_f32(scores, M, WencW2, (long long)i * DF, BencW2, (long long)i * Dc, delta, Dc, FFc);
    k_lnres2<<<M, 256, 0, stream>>>(cur_y, curb_y, delta, enc_lg, (long long)(i*2+1)*Dc, enc_lb, (long long)(i*2+1)*Dc, flag);
  }

  // ---- decoder ----
  for (int i = 0; i < 6; ++i) {
    int M = NB * LXc;
    for (int a = 0; a < 2; ++a) {
      long long wo = (long long)(i * 2 + a) * 4 * DD;
      long long bo = (long long)(i * 2 + a) * 4 * Dc;
      if (a == 0) {
        qkv8(curb_x, M, WdecA, wo, BdecA, bo, LXc);
      } else {
        proj_b16(curb_x, M, WdecA, wo, BdecA, bo, qbf, Dc, Dc, 0);        // grid 384 on gemm2
        proj_kv2(curb_y, NB * LYc, WdecA, wo + DD, BdecA, bo + Dc, LYc);  // grid 384 on gemm2
      }
      int Lk = a ? LYc : LXc;
      g_scores(qbf, LXc, kbf, Lk);
      k_softmax2<<<(NB * NH * LXc) / 4, 256, 0, stream>>>(scores, Lk, (long long)NB * NH * LXc);
      g_pv(LXc, Lk, 1);
      g_rel();
      proj_f32(ao2, M, WdecA, wo + 3 * DD, BdecA, bo + 3 * Dc, delta, Dc, Dc);  // grid 384 on gemm2
      k_lnres2<<<M, 256, 0, stream>>>(cur_x, curb_x, delta, dec_lg, (long long)(i*3+a)*Dc, dec_lb, (long long)(i*3+a)*Dc, flag);
    }
    b16_8(curb_x, M, WdecW1, (long long)i * DF, BdecW1, (long long)i * FFc, scores, FFc, Dc, 1);  // grid 384 gemm8
    proj_f32(scores, M, WdecW2, (long long)i * DF, BdecW2, (long long)i * Dc, delta, Dc, FFc);    // grid 384 gemm2
    k_lnres2<<<M, 256, 0, stream>>>(cur_x, curb_x, delta, dec_lg, (long long)(i*3+2)*Dc, dec_lb, (long long)(i*3+2)*Dc, flag);
  }

  k_emit<<<2048, 256, 0, stream>>>(cur_y, cur_x, d_out, flag, NYt, NYt + NXt);
}

// Round 6
// 3961.709 us; speedup vs baseline: 1.2417x; 1.1646x over previous
//
#include <hip/hip_runtime.h>

#define DEV __device__ __forceinline__

constexpr int NB  = 32;
constexpr int LXc = 256;
constexpr int LYc = 128;
constexpr int Dc  = 768;
constexpr int NH  = 12;
constexpr int FFc = 3072;

typedef unsigned short u16;
typedef float f32x4 __attribute__((ext_vector_type(4)));
typedef short s16x8 __attribute__((ext_vector_type(8)));

DEV u16 f2bf(float f) {
  unsigned u = __float_as_uint(f);
  u += 0x7FFFu + ((u >> 16) & 1u);
  return (u16)(u >> 16);
}
DEV float bf2f(u16 w) { return __uint_as_float(((unsigned)w) << 16); }
DEV float ldf(const void* p, long long i, int isbf) {
  return isbf ? bf2f(((const u16*)p)[i]) : ((const float*)p)[i];
}

DEV void gload16(const void* g, void* l) {
  __builtin_amdgcn_global_load_lds(
      (const __attribute__((address_space(1))) void*)g,
      (__attribute__((address_space(3))) void*)l, 16, 0, 0);
}
DEV void barx() {
  asm volatile("" ::: "memory");
  __builtin_amdgcn_s_barrier();
  asm volatile("" ::: "memory");
}

// ---------------- dtype detection ----------------
__global__ void k_detect(const u16* y, int* flag) {
  if (threadIdx.x == 0) {
    int cnt = 0;
    for (int i = 0; i < 256; ++i) {
      u16 w = y[i];
      int e = (w >> 7) & 0xFF;
      if (e == 0 || (e >= 112 && e <= 140)) cnt++;
    }
    *flag = (cnt >= 200) ? 1 : 0;
  }
}

__global__ void k_ingest2(const void* src, float* dst, u16* dstb, long long n, const int* flag) {
  int isbf = *flag;
  long long i = (long long)blockIdx.x * blockDim.x + threadIdx.x;
  long long st = (long long)gridDim.x * blockDim.x;
  for (; i < n; i += st) { float v = ldf(src, i, isbf); dst[i] = v; dstb[i] = f2bf(v); }
}

__global__ void k_cvt(const void* src, float* dst, long long n, const int* flag) {
  int isbf = *flag;
  long long i = (long long)blockIdx.x * blockDim.x + threadIdx.x;
  long long st = (long long)gridDim.x * blockDim.x;
  for (; i < n; i += st) dst[i] = ldf(src, i, isbf);
}

__global__ void k_emit(const float* ybuf, const float* xbuf, void* out,
                       const int* flag, long long ny, long long nt) {
  int isbf = *flag;
  long long i = (long long)blockIdx.x * blockDim.x + threadIdx.x;
  long long st = (long long)gridDim.x * blockDim.x;
  for (; i < nt; i += st) {
    float v = (i < ny) ? ybuf[i] : xbuf[i - ny];
    if (isbf) ((u16*)out)[i] = f2bf(v);
    else      ((float*)out)[i] = v;
  }
}

// ---------------- weight transpose+convert: [R][C] raw -> [C][R] bf16 ----------------
__global__ __launch_bounds__(256) void k_wt(const void* src, u16* dst, int R, int C, const int* flag) {
  int isbf = *flag;
  __shared__ u16 t[32][33];
  long long base = (long long)blockIdx.z * R * C;
  int c0 = blockIdx.x * 32, r0 = blockIdx.y * 32;
  int tx = threadIdx.x & 31, ty = threadIdx.x >> 5;
#pragma unroll
  for (int k = 0; k < 4; ++k) {
    int r = r0 + ty + k * 8;
    t[ty + k * 8][tx] = f2bf(ldf(src, base + (long long)r * C + (c0 + tx), isbf));
  }
  __syncthreads();
#pragma unroll
  for (int k = 0; k < 4; ++k) {
    int c = c0 + ty + k * 8;
    dst[base + (long long)c * R + (r0 + tx)] = t[tx][ty + k * 8];
  }
}

// ---------------- bbox cosine-sim + softmax (bf16 out) ----------------
__global__ __launch_bounds__(256) void k_bboxsim(const void* bbox, const int* flag, u16* sim) {
  int isbf = *flag;
  int b = blockIdx.x >> 8, i = blockIdx.x & 255;
  int j = threadIdx.x;
  long long base = (long long)b * LXc * 4;
  float a[4], c[4];
#pragma unroll
  for (int t = 0; t < 4; ++t) {
    a[t] = ldf(bbox, base + (long long)i * 4 + t, isbf);
    c[t] = ldf(bbox, base + (long long)j * 4 + t, isbf);
  }
  float dot = a[0]*c[0] + a[1]*c[1] + a[2]*c[2] + a[3]*c[3];
  float na  = sqrtf(a[0]*a[0] + a[1]*a[1] + a[2]*a[2] + a[3]*a[3]);
  float ncn = sqrtf(c[0]*c[0] + c[1]*c[1] + c[2]*c[2] + c[3]*c[3]);
  float v = dot / (na * ncn);
  __shared__ float r1[4], r2[4];
  float m = v;
  for (int o = 32; o; o >>= 1) m = fmaxf(m, __shfl_xor(m, o));
  if ((threadIdx.x & 63) == 0) r1[threadIdx.x >> 6] = m;
  __syncthreads();
  m = fmaxf(fmaxf(r1[0], r1[1]), fmaxf(r1[2], r1[3]));
  float e = __expf(v - m);
  float s = e;
  for (int o = 32; o; o >>= 1) s += __shfl_xor(s, o);
  if ((threadIdx.x & 63) == 0) r2[threadIdx.x >> 6] = s;
  __syncthreads();
  s = r2[0] + r2[1] + r2[2] + r2[3];
  sim[((long long)b * LXc + i) * LXc + j] = f2bf(e / s);
}

// ---------------- residual + layernorm (bf16 delta) -> f32 cur + bf16 mirror ----------------
__global__ __launch_bounds__(256) void k_lnres2(float* cur, u16* curb, const u16* delta,
                                                const void* g, long long gOff,
                                                const void* bb, long long bOff,
                                                const int* flag) {
  int isbf = *flag;
  long long row = blockIdx.x;
  float* xr = cur + row * Dc;
  const u16* dr = delta + row * Dc;
  int t = threadIdx.x;
  float v[3];
  float s = 0.f;
#pragma unroll
  for (int i = 0; i < 3; ++i) { int c = t + i * 256; v[i] = xr[c] + bf2f(dr[c]); s += v[i]; }
  __shared__ float r1[4], r2[4];
  for (int o = 32; o; o >>= 1) s += __shfl_xor(s, o);
  if ((t & 63) == 0) r1[t >> 6] = s;
  __syncthreads();
  float mean = (r1[0] + r1[1] + r1[2] + r1[3]) * (1.0f / 768.0f);
  float s2 = 0.f;
#pragma unroll
  for (int i = 0; i < 3; ++i) { float d = v[i] - mean; s2 += d * d; }
  for (int o = 32; o; o >>= 1) s2 += __shfl_xor(s2, o);
  if ((t & 63) == 0) r2[t >> 6] = s2;
  __syncthreads();
  float var = (r2[0] + r2[1] + r2[2] + r2[3]) * (1.0f / 768.0f);
  float rstd = rsqrtf(var + 1e-6f);
#pragma unroll
  for (int i = 0; i < 3; ++i) {
    int c = t + i * 256;
    float o = ldf(g, gOff + c, isbf) * (v[i] - mean) * rstd + ldf(bb, bOff + c, isbf);
    xr[c] = o;
    curb[row * Dc + c] = f2bf(o);
  }
}

// ---------------- fused flash attention ----------------
// One block per (qt, h, b): 4 waves, each owns 16 q-rows (64 rows/block).
// K-tile 64x64 and V^T-tile 64x64 staged via global_load_lds with T2 XOR swizzle;
// QK^T MFMA -> online softmax in-register -> P via padded LDS -> PV MFMA.
// DEC=1: writes O^T to aoT[b][h*64+dh][q] (256 q-stride). DEC=0: O to ao2[(b*Lq+q)][768].
template<int DEC>
__global__ __launch_bounds__(256) void k_attn(const u16* __restrict__ Q,
                                              const u16* __restrict__ Kb,
                                              const u16* __restrict__ Vt,
                                              u16* __restrict__ Out,
                                              int Lq, int Lk) {
  __shared__ __align__(16) u16 Kl[64 * 64];
  __shared__ __align__(16) u16 Vl[64 * 64];
  __shared__ __align__(16) u16 Pl[4][16][72];   // 144B row stride (16B aligned, 2-way banks)
  const int tid = threadIdx.x, wid = tid >> 6, lane = tid & 63;
  const int qt = blockIdx.x, h = blockIdx.y, b = blockIdx.z;
  const int q0 = qt * 64 + wid * 16;
  const int rl = lane & 15, sx = lane >> 4;
  const int srow = lane >> 3;
  const int scol8 = ((lane & 7) ^ srow) << 3;   // inverse-swizzled global elem col

  // Q fragments in registers (16 rows x 64 d)
  s16x8 qa[2];
  {
    const u16* qrow = Q + ((long long)b * Lq + q0 + rl) * Dc + h * 64;
    qa[0] = *(const s16x8*)(qrow + sx * 8);
    qa[1] = *(const s16x8*)(qrow + 32 + sx * 8);
  }
  f32x4 o[4] = {};
  float m[4], l[4];
#pragma unroll
  for (int e = 0; e < 4; ++e) { m[e] = -3.0e38f; l[e] = 0.f; }

  const long long kbase = (long long)b * Lk * Dc + h * 64;
  const long long vbase = ((long long)b * Dc + h * 64) * Lk;

  for (int k0 = 0; k0 < Lk; k0 += 64) {
    // stage K rows [kk][d] and V^T rows [dh][k] (8KB each)
#pragma unroll
    for (int g = 0; g < 2; ++g) {
      int chunk = g * 4 + wid;
      gload16(Kb + kbase + (long long)(k0 + chunk * 8 + srow) * Dc + scol8,
              (char*)Kl + chunk * 1024);
    }
#pragma unroll
    for (int g = 0; g < 2; ++g) {
      int chunk = g * 4 + wid;
      gload16(Vt + vbase + (long long)(chunk * 8 + srow) * Lk + k0 + scol8,
              (char*)Vl + chunk * 1024);
    }
    asm volatile("s_waitcnt vmcnt(0)" ::: "memory");
    barx();

    // QK^T: S[16 q][64 k], swizzled reads (2 lanes/bank)
    f32x4 s[4];
#pragma unroll
    for (int n = 0; n < 4; ++n) {
      s16x8 b0 = *(const s16x8*)((char*)Kl + (n * 16 + rl) * 128 + ((sx    ) ^ (rl & 7)) * 16);
      s16x8 b1 = *(const s16x8*)((char*)Kl + (n * 16 + rl) * 128 + ((sx + 4) ^ (rl & 7)) * 16);
      f32x4 acc = {};
      acc = __builtin_amdgcn_mfma_f32_16x16x32_bf16(qa[0], b0, acc, 0, 0, 0);
      acc = __builtin_amdgcn_mfma_f32_16x16x32_bf16(qa[1], b1, acc, 0, 0, 0);
      s[n] = acc;
    }
#pragma unroll
    for (int n = 0; n < 4; ++n)
#pragma unroll
      for (int e = 0; e < 4; ++e) s[n][e] *= 0.125f;

    // online softmax per row (rows = sx*4+e; row spread over 16 lanes w/ same sx)
#pragma unroll
    for (int e = 0; e < 4; ++e) {
      float v = fmaxf(fmaxf(s[0][e], s[1][e]), fmaxf(s[2][e], s[3][e]));
      v = fmaxf(v, __shfl_xor(v, 1));
      v = fmaxf(v, __shfl_xor(v, 2));
      v = fmaxf(v, __shfl_xor(v, 4));
      v = fmaxf(v, __shfl_xor(v, 8));
      float mn = fmaxf(m[e], v);
      float alpha = __expf(m[e] - mn);
      m[e] = mn;
      float ls = 0.f;
#pragma unroll
      for (int n = 0; n < 4; ++n) {
        float p = __expf(s[n][e] - mn);
        s[n][e] = p;
        ls += p;
      }
      ls += __shfl_xor(ls, 1);
      ls += __shfl_xor(ls, 2);
      ls += __shfl_xor(ls, 4);
      ls += __shfl_xor(ls, 8);
      l[e] = l[e] * alpha + ls;
#pragma unroll
      for (int n = 0; n < 4; ++n) o[n][e] *= alpha;
    }

    // P -> LDS (transpose to A-frag layout)
#pragma unroll
    for (int e = 0; e < 4; ++e)
#pragma unroll
      for (int n = 0; n < 4; ++n)
        Pl[wid][sx * 4 + e][n * 16 + rl] = f2bf(s[n][e]);
    barx();

    // PV: O[16 q][64 dh] += P @ V
    s16x8 pa0 = *(const s16x8*)&Pl[wid][rl][sx * 8];
    s16x8 pa1 = *(const s16x8*)&Pl[wid][rl][32 + sx * 8];
#pragma unroll
    for (int n = 0; n < 4; ++n) {
      s16x8 v0 = *(const s16x8*)((char*)Vl + (n * 16 + rl) * 128 + ((sx    ) ^ (rl & 7)) * 16);
      s16x8 v1 = *(const s16x8*)((char*)Vl + (n * 16 + rl) * 128 + ((sx + 4) ^ (rl & 7)) * 16);
      o[n] = __builtin_amdgcn_mfma_f32_16x16x32_bf16(pa0, v0, o[n], 0, 0, 0);
      o[n] = __builtin_amdgcn_mfma_f32_16x16x32_bf16(pa1, v1, o[n], 0, 0, 0);
    }
    barx();   // all Vl/Pl reads done before next stage
  }

#pragma unroll
  for (int e = 0; e < 4; ++e) l[e] = 1.0f / l[e];
  if (DEC) {
    u16* Op = Out + ((long long)b * Dc + h * 64) * LXc;
#pragma unroll
    for (int n = 0; n < 4; ++n) {
      union { u16 u[4]; uint2 d; } pk;
#pragma unroll
      for (int e = 0; e < 4; ++e) pk.u[e] = f2bf(o[n][e] * l[e]);
      *(uint2*)&Op[(long long)(n * 16 + rl) * LXc + q0 + sx * 4] = pk.d;
    }
  } else {
    u16* Op = Out + ((long long)b * Lq + q0) * Dc + h * 64;
#pragma unroll
    for (int n = 0; n < 4; ++n)
#pragma unroll
      for (int e = 0; e < 4; ++e)
        Op[(long long)(sx * 4 + e) * Dc + n * 16 + rl] = f2bf(o[n][e] * l[e]);
  }
}

// ---------------- GEMM param block ----------------
struct G2 {
  const u16* A; long long lda, sAb, sAh;
  const u16* W; long long ldw, sWb, sWh;
  const float* bias; long long bOff;
  void* C; long long ldc, sCb, sCh;
  void* Ck; void* Cv; int vSeg;
  int Hdim; float scale; int relu; int Lseq;
};

// ---------------- 128x128 2-phase MFMA GEMM ----------------
template<int BM, int BN, int MODE>
__global__ __launch_bounds__(256, 2) void gemm2(G2 p, int M, int N, int K) {
  constexpr int BK = 64;
  __shared__ __align__(16) u16 Al[BM * BK];
  __shared__ __align__(16) u16 Bl[BN * BK];
  const int tid = threadIdx.x, wid = tid >> 6, lane = tid & 63;
  const int z = blockIdx.z, zb = z / p.Hdim, zh = z % p.Hdim;
  int bx = blockIdx.x, by = blockIdx.y;
  if (gridDim.z == 1) {
    int gx = gridDim.x, nwg = gx * gridDim.y;
    int orig = by * gx + bx;
    int q = nwg >> 3, r = nwg & 7, xcd = orig & 7, lin = orig >> 3;
    int wg = (xcd < r ? xcd * (q + 1) : r * (q + 1) + (xcd - r) * q) + lin;
    bx = wg % gx; by = wg / gx;
  }
  const u16* A = p.A + (long long)zb * p.sAb + (long long)zh * p.sAh;
  const u16* W = p.W + (long long)zb * p.sWb + (long long)zh * p.sWh;
  const int m0 = by * BM, n0 = bx * BN;
  const int wr = wid >> 1, wc = wid & 1;
  constexpr int FM = BM / 32, FN = BN / 32;
  f32x4 acc[FM][FN] = {};
  const int lr = lane >> 3;
  const int lo = (lane & 7) * 16;

  for (int k0 = 0; k0 < K; k0 += BK) {
#pragma unroll
    for (int i = 0; i < BM / 32; ++i) {
      int chunk = wid * (BM / 32) + i;
      int row = chunk * 8 + lr;
      gload16((const char*)(A + (long long)(m0 + row) * p.lda + k0) + lo,
              (char*)Al + chunk * 1024);
    }
#pragma unroll
    for (int i = 0; i < BN / 32; ++i) {
      int chunk = wid * (BN / 32) + i;
      int row = chunk * 8 + lr;
      gload16((const char*)(W + (long long)(n0 + row) * p.ldw + k0) + lo,
              (char*)Bl + chunk * 1024);
    }
    __syncthreads();
#pragma unroll
    for (int ks = 0; ks < 2; ++ks) {
      s16x8 af[FM], bfr[FN];
      const int kc = ks * 32 + (lane >> 4) * 8;
      const int rl = lane & 15;
#pragma unroll
      for (int i = 0; i < FM; ++i) af[i]  = *(const s16x8*)&Al[(wr * (BM / 2) + i * 16 + rl) * BK + kc];
#pragma unroll
      for (int j = 0; j < FN; ++j) bfr[j] = *(const s16x8*)&Bl[(wc * (BN / 2) + j * 16 + rl) * BK + kc];
#pragma unroll
      for (int i = 0; i < FM; ++i)
#pragma unroll
        for (int j = 0; j < FN; ++j)
          acc[i][j] = __builtin_amdgcn_mfma_f32_16x16x32_bf16(af[i], bfr[j], acc[i][j], 0, 0, 0);
    }
    __syncthreads();
  }

  const int seg = (MODE == 4) ? (n0 / 768) : 0;
#pragma unroll
  for (int j = 0; j < FN; ++j) {
    int col = n0 + wc * (BN / 2) + j * 16 + (lane & 15);
    float bv = p.bias ? p.bias[p.bOff + col] : 0.f;
#pragma unroll
    for (int i = 0; i < FM; ++i) {
      int row0 = m0 + wr * (BM / 2) + i * 16 + (lane >> 4) * 4;
      if (MODE == 0) {
        u16* C = (u16*)p.C + (long long)zb * p.sCb + (long long)zh * p.sCh;
#pragma unroll
        for (int e = 0; e < 4; ++e) {
          float v = acc[i][j][e] * p.scale + bv;
          if (p.relu) v = fmaxf(v, 0.f);
          C[(long long)(row0 + e) * p.ldc + col] = f2bf(v);
        }
      } else {  // MODE 4: segment-routed QKV
        u16* outp = seg == 0 ? (u16*)p.C : (seg == 1 ? (u16*)p.Ck : (u16*)p.Cv);
        int c = col - seg * 768;
        if (seg == p.vSeg) {
          int b = row0 / p.Lseq, l = row0 % p.Lseq;
          union { u16 u[4]; uint2 d; } pk;
#pragma unroll
          for (int e = 0; e < 4; ++e) pk.u[e] = f2bf(acc[i][j][e] + bv);
          *(uint2*)&outp[((long long)b * Dc + c) * p.Lseq + l] = pk.d;
        } else {
#pragma unroll
          for (int e = 0; e < 4; ++e)
            outp[(long long)(row0 + e) * 768 + c] = f2bf(acc[i][j][e] + bv);
        }
      }
    }
  }
}

// ---------------- 256x256 phase-interleaved MFMA GEMM (T2+T3+T4+T5) ----------------
template<int MODE>
__global__ __launch_bounds__(512, 2) void gemm8(G2 p, int M, int N, int K) {
  extern __shared__ __align__(16) char sm[];
  const int tid = threadIdx.x, wid = tid >> 6, lane = tid & 63;
  const int wm = wid >> 2, wn = wid & 3;
  int bx = blockIdx.x, by = blockIdx.y;
  {
    int gx = gridDim.x, nwg = gx * gridDim.y;
    int orig = by * gx + bx;
    int q = nwg >> 3, r = nwg & 7, xcd = orig & 7, lin = orig >> 3;
    int wg = (xcd < r ? xcd * (q + 1) : r * (q + 1) + (xcd - r) * q) + lin;
    bx = wg % gx; by = wg / gx;
  }
  const int m0 = by * 256, n0 = bx * 256;
  const u16* Ag = p.A;
  const u16* Wg = p.W;
  const long long lda = p.lda, ldw = p.ldw;
  const int NT = K >> 6;

  const int srow = lane >> 3;
  const int scol = ((lane & 7) ^ srow) << 3;
  const int rl = lane & 15;
  const int lx = lane & 7;
  const int sx = lane >> 4;
  const int slotb0 = ((sx + 0) ^ lx) << 4;
  const int slotb1 = ((sx + 4) ^ lx) << 4;

  auto stage = [&](int t, int bufbase) {
    long long k0 = (long long)t << 6;
#pragma unroll
    for (int g = 0; g < 4; ++g) {
      int chunk = g * 8 + wid;
      gload16(Ag + (long long)(m0 + chunk * 8 + srow) * lda + k0 + scol,
              sm + bufbase + chunk * 1024);
    }
#pragma unroll
    for (int g = 0; g < 4; ++g) {
      int chunk = g * 8 + wid;
      gload16(Wg + (long long)(n0 + chunk * 8 + srow) * ldw + k0 + scol,
              sm + bufbase + 32768 + chunk * 1024);
    }
  };

  f32x4 acc[8][4] = {};
  s16x8 ar[4][2], br0[2][2], br1[2][2];

  stage(0, 0);
  asm volatile("s_waitcnt vmcnt(0)" ::: "memory");
  barx();

  for (int t = 0; t < NT; ++t) {
    const int bb = (t & 1) << 16;
    const char* aB = sm + bb;
    const char* bBf = sm + bb + 32768;

    auto ldA = [&](int h) {
      const int rbase = wm * 128 + h * 64 + rl;
#pragma unroll
      for (int i = 0; i < 4; ++i) {
        ar[i][0] = *(const s16x8*)(aB + (rbase + i * 16) * 128 + slotb0);
        ar[i][1] = *(const s16x8*)(aB + (rbase + i * 16) * 128 + slotb1);
      }
    };
    auto ldB = [&](int c, s16x8 (&br)[2][2]) {
      const int rbase = wn * 64 + c * 32 + rl;
#pragma unroll
      for (int j = 0; j < 2; ++j) {
        br[j][0] = *(const s16x8*)(bBf + (rbase + j * 16) * 128 + slotb0);
        br[j][1] = *(const s16x8*)(bBf + (rbase + j * 16) * 128 + slotb1);
      }
    };
    auto mm = [&](int ih, int jc, const s16x8 (&br)[2][2]) {
      __builtin_amdgcn_s_setprio(1);
#pragma unroll
      for (int ks = 0; ks < 2; ++ks)
#pragma unroll
        for (int i = 0; i < 4; ++i)
#pragma unroll
          for (int j = 0; j < 2; ++j)
            acc[ih * 4 + i][jc * 2 + j] = __builtin_amdgcn_mfma_f32_16x16x32_bf16(
                ar[i][ks], br[j][ks], acc[ih * 4 + i][jc * 2 + j], 0, 0, 0);
      __builtin_amdgcn_s_setprio(0);
    };

    ldA(0); ldB(0, br0);
    if (t + 1 < NT) stage(t + 1, bb ^ 65536);
    barx();
    mm(0, 0, br0);
    barx();
    ldB(1, br1);
    barx();
    mm(0, 1, br1);
    barx();
    ldA(1);
    barx();
    mm(1, 1, br1);
    barx();
    mm(1, 0, br0);
    if (t + 1 < NT) {
      asm volatile("s_waitcnt vmcnt(0)" ::: "memory");
      barx();
    }
  }

  const int seg = (MODE == 4) ? (n0 / 768) : 0;
#pragma unroll
  for (int j = 0; j < 4; ++j) {
    int col = n0 + wn * 64 + j * 16 + (lane & 15);
    float bv = p.bias ? p.bias[p.bOff + col] : 0.f;
#pragma unroll
    for (int i = 0; i < 8; ++i) {
      int row0 = m0 + wm * 128 + i * 16 + (lane >> 4) * 4;
      if (MODE == 0) {
        u16* C = (u16*)p.C;
#pragma unroll
        for (int e = 0; e < 4; ++e) {
          float v = acc[i][j][e] * p.scale + bv;
          if (p.relu) v = fmaxf(v, 0.f);
          C[(long long)(row0 + e) * p.ldc + col] = f2bf(v);
        }
      } else {  // MODE 4
        u16* outp = seg == 0 ? (u16*)p.C : (seg == 1 ? (u16*)p.Ck : (u16*)p.Cv);
        int c = col - seg * 768;
        if (seg == p.vSeg) {
          int b = row0 / p.Lseq, l = row0 % p.Lseq;
          union { u16 u[4]; uint2 d; } pk;
#pragma unroll
          for (int e = 0; e < 4; ++e) pk.u[e] = f2bf(acc[i][j][e] + bv);
          *(uint2*)&outp[((long long)b * Dc + c) * p.Lseq + l] = pk.d;
        } else {
#pragma unroll
          for (int e = 0; e < 4; ++e)
            outp[(long long)(row0 + e) * 768 + c] = f2bf(acc[i][j][e] + bv);
        }
      }
    }
  }
}

// ---------------- launch helpers ----------------
template<int BM, int BN, int MODE>
static void run_gemm(const G2& p, int M, int N, int K, int nz, hipStream_t st) {
  dim3 grid(N / BN, M / BM, nz);
  gemm2<BM, BN, MODE><<<grid, 256, 0, st>>>(p, M, N, K);
}

template<int MODE>
static void run_gemm8(const G2& p, int M, int N, int K, hipStream_t st) {
  dim3 grid(N / 256, M / 256, 1);
  gemm8<MODE><<<grid, 512, 131072, st>>>(p, M, N, K);
}

extern "C" void kernel_launch(void* const* d_in, const int* in_sizes, int n_in,
                              void* d_out, int out_size, void* d_ws, size_t ws_size,
                              hipStream_t stream) {
  (void)hipFuncSetAttribute((const void*)&gemm8<0>, hipFuncAttributeMaxDynamicSharedMemorySize, 131072);
  (void)hipFuncSetAttribute((const void*)&gemm8<4>, hipFuncAttributeMaxDynamicSharedMemorySize, 131072);

  const void* y_in  = d_in[0];
  const void* x_in  = d_in[1];
  const void* bbox  = d_in[5];
  const void* enc_aw = d_in[6];  const void* enc_ab = d_in[7];
  const void* enc_w1 = d_in[8];  const void* enc_b1 = d_in[9];
  const void* enc_w2 = d_in[10]; const void* enc_b2 = d_in[11];
  const void* enc_lg = d_in[12]; const void* enc_lb = d_in[13];
  const void* dec_aw = d_in[14]; const void* dec_ab = d_in[15];
  const void* dec_w1 = d_in[16]; const void* dec_b1 = d_in[17];
  const void* dec_w2 = d_in[18]; const void* dec_b2 = d_in[19];
  const void* dec_lg = d_in[20]; const void* dec_lb = d_in[21];

  char* base = (char*)d_ws;
  size_t off = 0;
  auto alloc = [&](size_t bytes) { void* p = base + off; off = (off + bytes + 255) & ~(size_t)255; return p; };
  int*  flag = (int*)alloc(256);
  const long long DD = (long long)Dc * Dc;
  const long long DF = (long long)Dc * FFc;
  u16* WencA  = (u16*)alloc(24 * DD * 2);
  u16* WencW1 = (u16*)alloc(6 * DF * 2);
  u16* WencW2 = (u16*)alloc(6 * DF * 2);
  u16* WdecA  = (u16*)alloc(48 * DD * 2);
  u16* WdecW1 = (u16*)alloc(6 * DF * 2);
  u16* WdecW2 = (u16*)alloc(6 * DF * 2);
  float* BencA  = (float*)alloc(24 * Dc * 4);
  float* BencW1 = (float*)alloc(6 * FFc * 4);
  float* BencW2 = (float*)alloc(6 * Dc * 4);
  float* BdecA  = (float*)alloc(48 * Dc * 4);
  float* BdecW1 = (float*)alloc(6 * FFc * 4);
  float* BdecW2 = (float*)alloc(6 * Dc * 4);
  const long long NYt = (long long)NB * LYc * Dc;
  const long long NXt = (long long)NB * LXc * Dc;
  float* cur_y  = (float*)alloc(NYt * 4);
  float* cur_x  = (float*)alloc(NXt * 4);
  u16*   curb_y = (u16*)alloc(NYt * 2);
  u16*   curb_x = (u16*)alloc(NXt * 2);
  u16*   simb   = (u16*)alloc((long long)NB * LXc * LXc * 2);
  u16*   qbf    = (u16*)alloc(NXt * 2);
  u16*   kbf    = (u16*)alloc(NXt * 2);
  u16*   vT     = (u16*)alloc(NXt * 2);
  u16*   deltab = (u16*)alloc(NXt * 2);
  u16*   aoT    = (u16*)alloc(NXt * 2);
  u16*   ao2    = (u16*)alloc(NXt * 2);
  u16*   ffmid  = (u16*)alloc((long long)NB * LXc * FFc * 2);

  k_detect<<<1, 64, 0, stream>>>((const u16*)y_in, flag);
  k_ingest2<<<1024, 256, 0, stream>>>(y_in, cur_y, curb_y, NYt, flag);
  k_ingest2<<<1024, 256, 0, stream>>>(x_in, cur_x, curb_x, NXt, flag);
  k_bboxsim<<<NB * LXc, 256, 0, stream>>>(bbox, flag, simb);
  k_wt<<<dim3(Dc/32, Dc/32, 24), 256, 0, stream>>>(enc_aw, WencA, Dc, Dc, flag);
  k_wt<<<dim3(FFc/32, Dc/32, 6), 256, 0, stream>>>(enc_w1, WencW1, Dc, FFc, flag);
  k_wt<<<dim3(Dc/32, FFc/32, 6), 256, 0, stream>>>(enc_w2, WencW2, FFc, Dc, flag);
  k_wt<<<dim3(Dc/32, Dc/32, 48), 256, 0, stream>>>(dec_aw, WdecA, Dc, Dc, flag);
  k_wt<<<dim3(FFc/32, Dc/32, 6), 256, 0, stream>>>(dec_w1, WdecW1, Dc, FFc, flag);
  k_wt<<<dim3(Dc/32, FFc/32, 6), 256, 0, stream>>>(dec_w2, WdecW2, FFc, Dc, flag);
  k_cvt<<<32, 256, 0, stream>>>(enc_ab, BencA, 24 * Dc, flag);
  k_cvt<<<32, 256, 0, stream>>>(enc_b1, BencW1, 6 * FFc, flag);
  k_cvt<<<32, 256, 0, stream>>>(enc_b2, BencW2, 6 * Dc, flag);
  k_cvt<<<32, 256, 0, stream>>>(dec_ab, BdecA, 48 * Dc, flag);
  k_cvt<<<32, 256, 0, stream>>>(dec_b1, BdecW1, 6 * FFc, flag);
  k_cvt<<<32, 256, 0, stream>>>(dec_b2, BdecW2, 6 * Dc, flag);

  // ---- helpers ----
  auto qkv8 = [&](const u16* A, int M, const u16* Wt, long long wOff,
                  const float* bias, long long bOff, int Lseq) {
    G2 p{}; p.A = A; p.lda = Dc; p.W = Wt + wOff; p.ldw = Dc;
    p.bias = bias; p.bOff = bOff;
    p.C = qbf; p.Ck = kbf; p.Cv = vT; p.vSeg = 2;
    p.Hdim = 1; p.scale = 1.f; p.Lseq = Lseq;
    run_gemm8<4>(p, M, 3 * Dc, Dc, stream);
  };
  auto proj_kv2 = [&](const u16* A, int M, const u16* Wt, long long wOff,
                      const float* bias, long long bOff, int Lseq) {
    G2 p{}; p.A = A; p.lda = Dc; p.W = Wt + wOff; p.ldw = Dc;
    p.bias = bias; p.bOff = bOff;
    p.C = kbf; p.Ck = vT; p.vSeg = 1;
    p.Hdim = 1; p.scale = 1.f; p.Lseq = Lseq;
    run_gemm<128, 128, 4>(p, M, 2 * Dc, Dc, 1, stream);
  };
  auto b16_8 = [&](const u16* A, int M, const u16* Wt, long long wOff,
                   const float* bias, long long bOff, u16* C, int N, int K, int relu) {
    G2 p{}; p.A = A; p.lda = K; p.W = Wt + wOff; p.ldw = K;
    p.bias = bias; p.bOff = bOff; p.C = C; p.ldc = N;
    p.Hdim = 1; p.scale = 1.f; p.relu = relu;
    run_gemm8<0>(p, M, N, K, stream);
  };
  auto proj_b16 = [&](const u16* A, int M, const u16* Wt, long long wOff,
                      const float* bias, long long bOff, u16* C, int N, int K, int relu) {
    G2 p{}; p.A = A; p.lda = K; p.W = Wt + wOff; p.ldw = K;
    p.bias = bias; p.bOff = bOff; p.C = C; p.ldc = N;
    p.Hdim = 1; p.scale = 1.f; p.relu = relu;
    run_gemm<128, 128, 0>(p, M, N, K, 1, stream);
  };
  auto g_rel = [&]() {
    G2 p{}; p.A = simb; p.lda = LXc; p.sAb = (long long)LXc * LXc;
    p.W = aoT; p.ldw = LXc; p.sWb = (long long)Dc * LXc;
    p.C = ao2; p.ldc = Dc; p.sCb = (long long)LXc * Dc;
    p.Hdim = 1; p.scale = 1.f;
    run_gemm<128, 128, 0>(p, LXc, Dc, LXc, NB, stream);
  };

  // ---- encoder ----
  for (int i = 0; i < 6; ++i) {
    int M = NB * LYc;
    long long wo = (long long)i * 4 * DD, bo = (long long)i * 4 * Dc;
    qkv8(curb_y, M, WencA, wo, BencA, bo, LYc);
    k_attn<0><<<dim3(LYc / 64, NH, NB), 256, 0, stream>>>(qbf, kbf, vT, ao2, LYc, LYc);
    proj_b16(ao2, M, WencA, wo + 3 * DD, BencA, bo + 3 * Dc, deltab, Dc, Dc, 0);
    k_lnres2<<<M, 256, 0, stream>>>(cur_y, curb_y, deltab, enc_lg, (long long)(i*2+0)*Dc, enc_lb, (long long)(i*2+0)*Dc, flag);
    b16_8(curb_y, M, WencW1, (long long)i * DF, BencW1, (long long)i * FFc, ffmid, FFc, Dc, 1);
    proj_b16(ffmid, M, WencW2, (long long)i * DF, BencW2, (long long)i * Dc, deltab, Dc, FFc, 0);
    k_lnres2<<<M, 256, 0, stream>>>(cur_y, curb_y, deltab, enc_lg, (long long)(i*2+1)*Dc, enc_lb, (long long)(i*2+1)*Dc, flag);
  }

  // ---- decoder ----
  for (int i = 0; i < 6; ++i) {
    int M = NB * LXc;
    for (int a = 0; a < 2; ++a) {
      long long wo = (long long)(i * 2 + a) * 4 * DD;
      long long bo = (long long)(i * 2 + a) * 4 * Dc;
      int Lk;
      if (a == 0) {
        qkv8(curb_x, M, WdecA, wo, BdecA, bo, LXc);
        Lk = LXc;
      } else {
        proj_b16(curb_x, M, WdecA, wo, BdecA, bo, qbf, Dc, Dc, 0);
        proj_kv2(curb_y, NB * LYc, WdecA, wo + DD, BdecA, bo + Dc, LYc);
        Lk = LYc;
      }
      k_attn<1><<<dim3(LXc / 64, NH, NB), 256, 0, stream>>>(qbf, kbf, vT, aoT, LXc, Lk);
      g_rel();
      proj_b16(ao2, M, WdecA, wo + 3 * DD, BdecA, bo + 3 * Dc, deltab, Dc, Dc, 0);
      k_lnres2<<<M, 256, 0, stream>>>(cur_x, curb_x, deltab, dec_lg, (long long)(i*3+a)*Dc, dec_lb, (long long)(i*3+a)*Dc, flag);
    }
    b16_8(curb_x, M, WdecW1, (long long)i * DF, BdecW1, (long long)i * FFc, ffmid, FFc, Dc, 1);
    proj_b16(ffmid, M, WdecW2, (long long)i * DF, BdecW2, (long long)i * Dc, deltab, Dc, FFc, 0);
    k_lnres2<<<M, 256, 0, stream>>>(cur_x, curb_x, deltab, dec_lg, (long long)(i*3+2)*Dc, dec_lb, (long long)(i*3+2)*Dc, flag);
  }

  k_emit<<<2048, 256, 0, stream>>>(cur_y, cur_x, d_out, flag, NYt, NYt + NXt);
}

// Round 7
// 3487.574 us; speedup vs baseline: 1.4105x; 1.1359x over previous
//
#include <hip/hip_runtime.h>

#define DEV __device__ __forceinline__

constexpr int NB  = 32;
constexpr int LXc = 256;
constexpr int LYc = 128;
constexpr int Dc  = 768;
constexpr int NH  = 12;
constexpr int FFc = 3072;

typedef unsigned short u16;
typedef float f32x4 __attribute__((ext_vector_type(4)));
typedef short s16x8 __attribute__((ext_vector_type(8)));

DEV u16 f2bf(float f) {
  unsigned u = __float_as_uint(f);
  u += 0x7FFFu + ((u >> 16) & 1u);
  return (u16)(u >> 16);
}
DEV float bf2f(u16 w) { return __uint_as_float(((unsigned)w) << 16); }
DEV float ldf(const void* p, long long i, int isbf) {
  return isbf ? bf2f(((const u16*)p)[i]) : ((const float*)p)[i];
}

DEV void gload16(const void* g, void* l) {
  __builtin_amdgcn_global_load_lds(
      (const __attribute__((address_space(1))) void*)g,
      (__attribute__((address_space(3))) void*)l, 16, 0, 0);
}
DEV void barx() {
  asm volatile("" ::: "memory");
  __builtin_amdgcn_s_barrier();
  asm volatile("" ::: "memory");
}

// ---------------- dtype detection ----------------
__global__ void k_detect(const u16* y, int* flag) {
  if (threadIdx.x == 0) {
    int cnt = 0;
    for (int i = 0; i < 256; ++i) {
      u16 w = y[i];
      int e = (w >> 7) & 0xFF;
      if (e == 0 || (e >= 112 && e <= 140)) cnt++;
    }
    *flag = (cnt >= 200) ? 1 : 0;
  }
}

// raw -> bf16 stream
__global__ void k_ingest_b(const void* src, u16* dst, long long n, const int* flag) {
  int isbf = *flag;
  long long i = (long long)blockIdx.x * blockDim.x + threadIdx.x;
  long long st = (long long)gridDim.x * blockDim.x;
  for (; i < n; i += st) dst[i] = isbf ? ((const u16*)src)[i] : f2bf(((const float*)src)[i]);
}

__global__ void k_cvt(const void* src, float* dst, long long n, const int* flag) {
  int isbf = *flag;
  long long i = (long long)blockIdx.x * blockDim.x + threadIdx.x;
  long long st = (long long)gridDim.x * blockDim.x;
  for (; i < n; i += st) dst[i] = ldf(src, i, isbf);
}

__global__ void k_emit(const u16* ybuf, const u16* xbuf, void* out,
                       const int* flag, long long ny, long long nt) {
  int isbf = *flag;
  long long i = (long long)blockIdx.x * blockDim.x + threadIdx.x;
  long long st = (long long)gridDim.x * blockDim.x;
  for (; i < nt; i += st) {
    u16 v = (i < ny) ? ybuf[i] : xbuf[i - ny];
    if (isbf) ((u16*)out)[i] = v;
    else      ((float*)out)[i] = bf2f(v);
  }
}

// ---------------- weight transpose+convert: [R][C] raw -> [C][R] bf16 ----------------
__global__ __launch_bounds__(256) void k_wt(const void* src, u16* dst, int R, int C, const int* flag) {
  int isbf = *flag;
  __shared__ u16 t[32][33];
  long long base = (long long)blockIdx.z * R * C;
  int c0 = blockIdx.x * 32, r0 = blockIdx.y * 32;
  int tx = threadIdx.x & 31, ty = threadIdx.x >> 5;
#pragma unroll
  for (int k = 0; k < 4; ++k) {
    int r = r0 + ty + k * 8;
    t[ty + k * 8][tx] = f2bf(ldf(src, base + (long long)r * C + (c0 + tx), isbf));
  }
  __syncthreads();
#pragma unroll
  for (int k = 0; k < 4; ++k) {
    int c = c0 + ty + k * 8;
    dst[base + (long long)c * R + (r0 + tx)] = t[tx][ty + k * 8];
  }
}

// ---------------- bbox cosine-sim + softmax (bf16 out) ----------------
__global__ __launch_bounds__(256) void k_bboxsim(const void* bbox, const int* flag, u16* sim) {
  int isbf = *flag;
  int b = blockIdx.x >> 8, i = blockIdx.x & 255;
  int j = threadIdx.x;
  long long base = (long long)b * LXc * 4;
  float a[4], c[4];
#pragma unroll
  for (int t = 0; t < 4; ++t) {
    a[t] = ldf(bbox, base + (long long)i * 4 + t, isbf);
    c[t] = ldf(bbox, base + (long long)j * 4 + t, isbf);
  }
  float dot = a[0]*c[0] + a[1]*c[1] + a[2]*c[2] + a[3]*c[3];
  float na  = sqrtf(a[0]*a[0] + a[1]*a[1] + a[2]*a[2] + a[3]*a[3]);
  float ncn = sqrtf(c[0]*c[0] + c[1]*c[1] + c[2]*c[2] + c[3]*c[3]);
  float v = dot / (na * ncn);
  __shared__ float r1[4], r2[4];
  float m = v;
  for (int o = 32; o; o >>= 1) m = fmaxf(m, __shfl_xor(m, o));
  if ((threadIdx.x & 63) == 0) r1[threadIdx.x >> 6] = m;
  __syncthreads();
  m = fmaxf(fmaxf(r1[0], r1[1]), fmaxf(r1[2], r1[3]));
  float e = __expf(v - m);
  float s = e;
  for (int o = 32; o; o >>= 1) s += __shfl_xor(s, o);
  if ((threadIdx.x & 63) == 0) r2[threadIdx.x >> 6] = s;
  __syncthreads();
  s = r2[0] + r2[1] + r2[2] + r2[3];
  sim[((long long)b * LXc + i) * LXc + j] = f2bf(e / s);
}

// ---------------- residual + layernorm, all-bf16 stream (f32 math) ----------------
__global__ __launch_bounds__(256) void k_lnres3(u16* curb, const u16* delta,
                                                const void* g, long long gOff,
                                                const void* bb, long long bOff,
                                                const int* flag) {
  int isbf = *flag;
  long long row = blockIdx.x;
  u16* xr = curb + row * Dc;
  const u16* dr = delta + row * Dc;
  int t = threadIdx.x;
  float v[3];
  float s = 0.f;
#pragma unroll
  for (int i = 0; i < 3; ++i) { int c = t + i * 256; v[i] = bf2f(xr[c]) + bf2f(dr[c]); s += v[i]; }
  __shared__ float r1[4], r2[4];
  for (int o = 32; o; o >>= 1) s += __shfl_xor(s, o);
  if ((t & 63) == 0) r1[t >> 6] = s;
  __syncthreads();
  float mean = (r1[0] + r1[1] + r1[2] + r1[3]) * (1.0f / 768.0f);
  float s2 = 0.f;
#pragma unroll
  for (int i = 0; i < 3; ++i) { float d = v[i] - mean; s2 += d * d; }
  for (int o = 32; o; o >>= 1) s2 += __shfl_xor(s2, o);
  if ((t & 63) == 0) r2[t >> 6] = s2;
  __syncthreads();
  float var = (r2[0] + r2[1] + r2[2] + r2[3]) * (1.0f / 768.0f);
  float rstd = rsqrtf(var + 1e-6f);
#pragma unroll
  for (int i = 0; i < 3; ++i) {
    int c = t + i * 256;
    float o = ldf(g, gOff + c, isbf) * (v[i] - mean) * rstd + ldf(bb, bOff + c, isbf);
    xr[c] = f2bf(o);
  }
}

// ---------------- fused flash attention ----------------
// One block per (qt, h, b): 4 waves, each owns 16 q-rows (64 rows/block).
template<int DEC>
__global__ __launch_bounds__(256) void k_attn(const u16* __restrict__ Q,
                                              const u16* __restrict__ Kb,
                                              const u16* __restrict__ Vt,
                                              u16* __restrict__ Out,
                                              int Lq, int Lk) {
  __shared__ __align__(16) u16 Kl[64 * 64];
  __shared__ __align__(16) u16 Vl[64 * 64];
  __shared__ __align__(16) u16 Pl[4][16][72];
  const int tid = threadIdx.x, wid = tid >> 6, lane = tid & 63;
  const int qt = blockIdx.x, h = blockIdx.y, b = blockIdx.z;
  const int q0 = qt * 64 + wid * 16;
  const int rl = lane & 15, sx = lane >> 4;
  const int srow = lane >> 3;
  const int scol8 = ((lane & 7) ^ srow) << 3;

  s16x8 qa[2];
  {
    const u16* qrow = Q + ((long long)b * Lq + q0 + rl) * Dc + h * 64;
    qa[0] = *(const s16x8*)(qrow + sx * 8);
    qa[1] = *(const s16x8*)(qrow + 32 + sx * 8);
  }
  f32x4 o[4] = {};
  float m[4], l[4];
#pragma unroll
  for (int e = 0; e < 4; ++e) { m[e] = -3.0e38f; l[e] = 0.f; }

  const long long kbase = (long long)b * Lk * Dc + h * 64;
  const long long vbase = ((long long)b * Dc + h * 64) * Lk;

  for (int k0 = 0; k0 < Lk; k0 += 64) {
#pragma unroll
    for (int g = 0; g < 2; ++g) {
      int chunk = g * 4 + wid;
      gload16(Kb + kbase + (long long)(k0 + chunk * 8 + srow) * Dc + scol8,
              (char*)Kl + chunk * 1024);
    }
#pragma unroll
    for (int g = 0; g < 2; ++g) {
      int chunk = g * 4 + wid;
      gload16(Vt + vbase + (long long)(chunk * 8 + srow) * Lk + k0 + scol8,
              (char*)Vl + chunk * 1024);
    }
    asm volatile("s_waitcnt vmcnt(0)" ::: "memory");
    barx();

    f32x4 s[4];
#pragma unroll
    for (int n = 0; n < 4; ++n) {
      s16x8 b0 = *(const s16x8*)((char*)Kl + (n * 16 + rl) * 128 + ((sx    ) ^ (rl & 7)) * 16);
      s16x8 b1 = *(const s16x8*)((char*)Kl + (n * 16 + rl) * 128 + ((sx + 4) ^ (rl & 7)) * 16);
      f32x4 acc = {};
      acc = __builtin_amdgcn_mfma_f32_16x16x32_bf16(qa[0], b0, acc, 0, 0, 0);
      acc = __builtin_amdgcn_mfma_f32_16x16x32_bf16(qa[1], b1, acc, 0, 0, 0);
      s[n] = acc;
    }
#pragma unroll
    for (int n = 0; n < 4; ++n)
#pragma unroll
      for (int e = 0; e < 4; ++e) s[n][e] *= 0.125f;

#pragma unroll
    for (int e = 0; e < 4; ++e) {
      float v = fmaxf(fmaxf(s[0][e], s[1][e]), fmaxf(s[2][e], s[3][e]));
      v = fmaxf(v, __shfl_xor(v, 1));
      v = fmaxf(v, __shfl_xor(v, 2));
      v = fmaxf(v, __shfl_xor(v, 4));
      v = fmaxf(v, __shfl_xor(v, 8));
      float mn = fmaxf(m[e], v);
      float alpha = __expf(m[e] - mn);
      m[e] = mn;
      float ls = 0.f;
#pragma unroll
      for (int n = 0; n < 4; ++n) {
        float p = __expf(s[n][e] - mn);
        s[n][e] = p;
        ls += p;
      }
      ls += __shfl_xor(ls, 1);
      ls += __shfl_xor(ls, 2);
      ls += __shfl_xor(ls, 4);
      ls += __shfl_xor(ls, 8);
      l[e] = l[e] * alpha + ls;
#pragma unroll
      for (int n = 0; n < 4; ++n) o[n][e] *= alpha;
    }

#pragma unroll
    for (int e = 0; e < 4; ++e)
#pragma unroll
      for (int n = 0; n < 4; ++n)
        Pl[wid][sx * 4 + e][n * 16 + rl] = f2bf(s[n][e]);
    barx();

    s16x8 pa0 = *(const s16x8*)&Pl[wid][rl][sx * 8];
    s16x8 pa1 = *(const s16x8*)&Pl[wid][rl][32 + sx * 8];
#pragma unroll
    for (int n = 0; n < 4; ++n) {
      s16x8 v0 = *(const s16x8*)((char*)Vl + (n * 16 + rl) * 128 + ((sx    ) ^ (rl & 7)) * 16);
      s16x8 v1 = *(const s16x8*)((char*)Vl + (n * 16 + rl) * 128 + ((sx + 4) ^ (rl & 7)) * 16);
      o[n] = __builtin_amdgcn_mfma_f32_16x16x32_bf16(pa0, v0, o[n], 0, 0, 0);
      o[n] = __builtin_amdgcn_mfma_f32_16x16x32_bf16(pa1, v1, o[n], 0, 0, 0);
    }
    barx();
  }

#pragma unroll
  for (int e = 0; e < 4; ++e) l[e] = 1.0f / l[e];
  if (DEC) {
    u16* Op = Out + ((long long)b * Dc + h * 64) * LXc;
#pragma unroll
    for (int n = 0; n < 4; ++n) {
      union { u16 u[4]; uint2 d; } pk;
#pragma unroll
      for (int e = 0; e < 4; ++e) pk.u[e] = f2bf(o[n][e] * l[e]);
      *(uint2*)&Op[(long long)(n * 16 + rl) * LXc + q0 + sx * 4] = pk.d;
    }
  } else {
    u16* Op = Out + ((long long)b * Lq + q0) * Dc + h * 64;
#pragma unroll
    for (int n = 0; n < 4; ++n)
#pragma unroll
      for (int e = 0; e < 4; ++e)
        Op[(long long)(sx * 4 + e) * Dc + n * 16 + rl] = f2bf(o[n][e] * l[e]);
  }
}

// ---------------- GEMM param block ----------------
struct G2 {
  const u16* A; long long lda, sAb, sAh;
  const u16* W; long long ldw, sWb, sWh;
  const float* bias; long long bOff;
  void* C; long long ldc, sCb, sCh;
  void* Ck; void* Cv; int vSeg;
  int Hdim; float scale; int relu; int Lseq;
};

// ---------------- 128xBN 2-phase MFMA GEMM ----------------
// MODE 0: bf16 C[row][col], optional relu.  MODE 4: segment-routed QKV.
template<int BM, int BN, int MODE>
__global__ __launch_bounds__(256, 2) void gemm2(G2 p, int M, int N, int K) {
  constexpr int BK = 64;
  __shared__ __align__(16) u16 Al[BM * BK];
  __shared__ __align__(16) u16 Bl[BN * BK];
  const int tid = threadIdx.x, wid = tid >> 6, lane = tid & 63;
  const int z = blockIdx.z, zb = z / p.Hdim, zh = z % p.Hdim;
  int bx = blockIdx.x, by = blockIdx.y;
  if (gridDim.z == 1) {
    int gx = gridDim.x, nwg = gx * gridDim.y;
    int orig = by * gx + bx;
    int q = nwg >> 3, r = nwg & 7, xcd = orig & 7, lin = orig >> 3;
    int wg = (xcd < r ? xcd * (q + 1) : r * (q + 1) + (xcd - r) * q) + lin;
    bx = wg % gx; by = wg / gx;
  }
  const u16* A = p.A + (long long)zb * p.sAb + (long long)zh * p.sAh;
  const u16* W = p.W + (long long)zb * p.sWb + (long long)zh * p.sWh;
  const int m0 = by * BM, n0 = bx * BN;
  const int wr = wid >> 1, wc = wid & 1;
  constexpr int FM = BM / 32, FN = BN / 32;
  f32x4 acc[FM][FN] = {};
  const int lr = lane >> 3;
  const int lo = (lane & 7) * 16;

  for (int k0 = 0; k0 < K; k0 += BK) {
#pragma unroll
    for (int i = 0; i < BM / 32; ++i) {
      int chunk = wid * (BM / 32) + i;
      int row = chunk * 8 + lr;
      gload16((const char*)(A + (long long)(m0 + row) * p.lda + k0) + lo,
              (char*)Al + chunk * 1024);
    }
#pragma unroll
    for (int i = 0; i < BN / 32; ++i) {
      int chunk = wid * (BN / 32) + i;
      int row = chunk * 8 + lr;
      gload16((const char*)(W + (long long)(n0 + row) * p.ldw + k0) + lo,
              (char*)Bl + chunk * 1024);
    }
    __syncthreads();
#pragma unroll
    for (int ks = 0; ks < 2; ++ks) {
      s16x8 af[FM], bfr[FN];
      const int kc = ks * 32 + (lane >> 4) * 8;
      const int rl = lane & 15;
#pragma unroll
      for (int i = 0; i < FM; ++i) af[i]  = *(const s16x8*)&Al[(wr * (BM / 2) + i * 16 + rl) * BK + kc];
#pragma unroll
      for (int j = 0; j < FN; ++j) bfr[j] = *(const s16x8*)&Bl[(wc * (BN / 2) + j * 16 + rl) * BK + kc];
#pragma unroll
      for (int i = 0; i < FM; ++i)
#pragma unroll
        for (int j = 0; j < FN; ++j)
          acc[i][j] = __builtin_amdgcn_mfma_f32_16x16x32_bf16(af[i], bfr[j], acc[i][j], 0, 0, 0);
    }
    __syncthreads();
  }

  const int seg = (MODE == 4) ? (n0 / 768) : 0;
#pragma unroll
  for (int j = 0; j < FN; ++j) {
    int col = n0 + wc * (BN / 2) + j * 16 + (lane & 15);
    float bv = p.bias ? p.bias[p.bOff + col] : 0.f;
#pragma unroll
    for (int i = 0; i < FM; ++i) {
      int row0 = m0 + wr * (BM / 2) + i * 16 + (lane >> 4) * 4;
      if (MODE == 0) {
        u16* C = (u16*)p.C + (long long)zb * p.sCb + (long long)zh * p.sCh;
#pragma unroll
        for (int e = 0; e < 4; ++e) {
          float v = acc[i][j][e] * p.scale + bv;
          if (p.relu) v = fmaxf(v, 0.f);
          C[(long long)(row0 + e) * p.ldc + col] = f2bf(v);
        }
      } else {  // MODE 4: segment-routed QKV
        u16* outp = seg == 0 ? (u16*)p.C : (seg == 1 ? (u16*)p.Ck : (u16*)p.Cv);
        int c = col - seg * 768;
        if (seg == p.vSeg) {
          int b = row0 / p.Lseq, l = row0 % p.Lseq;
          union { u16 u[4]; uint2 d; } pk;
#pragma unroll
          for (int e = 0; e < 4; ++e) pk.u[e] = f2bf(acc[i][j][e] + bv);
          *(uint2*)&outp[((long long)b * Dc + c) * p.Lseq + l] = pk.d;
        } else {
#pragma unroll
          for (int e = 0; e < 4; ++e)
            outp[(long long)(row0 + e) * 768 + c] = f2bf(acc[i][j][e] + bv);
        }
      }
    }
  }
}

// ---------------- launch helpers ----------------
template<int BM, int BN, int MODE>
static void run_gemm(const G2& p, int M, int N, int K, int nz, hipStream_t st) {
  dim3 grid(N / BN, M / BM, nz);
  gemm2<BM, BN, MODE><<<grid, 256, 0, st>>>(p, M, N, K);
}

extern "C" void kernel_launch(void* const* d_in, const int* in_sizes, int n_in,
                              void* d_out, int out_size, void* d_ws, size_t ws_size,
                              hipStream_t stream) {
  const void* y_in  = d_in[0];
  const void* x_in  = d_in[1];
  const void* bbox  = d_in[5];
  const void* enc_aw = d_in[6];  const void* enc_ab = d_in[7];
  const void* enc_w1 = d_in[8];  const void* enc_b1 = d_in[9];
  const void* enc_w2 = d_in[10]; const void* enc_b2 = d_in[11];
  const void* enc_lg = d_in[12]; const void* enc_lb = d_in[13];
  const void* dec_aw = d_in[14]; const void* dec_ab = d_in[15];
  const void* dec_w1 = d_in[16]; const void* dec_b1 = d_in[17];
  const void* dec_w2 = d_in[18]; const void* dec_b2 = d_in[19];
  const void* dec_lg = d_in[20]; const void* dec_lb = d_in[21];

  char* base = (char*)d_ws;
  size_t off = 0;
  auto alloc = [&](size_t bytes) { void* p = base + off; off = (off + bytes + 255) & ~(size_t)255; return p; };
  int*  flag = (int*)alloc(256);
  const long long DD = (long long)Dc * Dc;
  const long long DF = (long long)Dc * FFc;
  u16* WencA  = (u16*)alloc(24 * DD * 2);
  u16* WencW1 = (u16*)alloc(6 * DF * 2);
  u16* WencW2 = (u16*)alloc(6 * DF * 2);
  u16* WdecA  = (u16*)alloc(48 * DD * 2);
  u16* WdecW1 = (u16*)alloc(6 * DF * 2);
  u16* WdecW2 = (u16*)alloc(6 * DF * 2);
  float* BencA  = (float*)alloc(24 * Dc * 4);
  float* BencW1 = (float*)alloc(6 * FFc * 4);
  float* BencW2 = (float*)alloc(6 * Dc * 4);
  float* BdecA  = (float*)alloc(48 * Dc * 4);
  float* BdecW1 = (float*)alloc(6 * FFc * 4);
  float* BdecW2 = (float*)alloc(6 * Dc * 4);
  const long long NYt = (long long)NB * LYc * Dc;
  const long long NXt = (long long)NB * LXc * Dc;
  u16*   curb_y = (u16*)alloc(NYt * 2);
  u16*   curb_x = (u16*)alloc(NXt * 2);
  u16*   simb   = (u16*)alloc((long long)NB * LXc * LXc * 2);
  u16*   qbf    = (u16*)alloc(NXt * 2);
  u16*   kbf    = (u16*)alloc(NXt * 2);
  u16*   vT     = (u16*)alloc(NXt * 2);
  u16*   deltab = (u16*)alloc(NXt * 2);
  u16*   aoT    = (u16*)alloc(NXt * 2);
  u16*   ao2    = (u16*)alloc(NXt * 2);
  u16*   ffmid  = (u16*)alloc((long long)NB * LXc * FFc * 2);

  k_detect<<<1, 64, 0, stream>>>((const u16*)y_in, flag);
  k_ingest_b<<<1024, 256, 0, stream>>>(y_in, curb_y, NYt, flag);
  k_ingest_b<<<1024, 256, 0, stream>>>(x_in, curb_x, NXt, flag);
  k_bboxsim<<<NB * LXc, 256, 0, stream>>>(bbox, flag, simb);
  k_wt<<<dim3(Dc/32, Dc/32, 24), 256, 0, stream>>>(enc_aw, WencA, Dc, Dc, flag);
  k_wt<<<dim3(FFc/32, Dc/32, 6), 256, 0, stream>>>(enc_w1, WencW1, Dc, FFc, flag);
  k_wt<<<dim3(Dc/32, FFc/32, 6), 256, 0, stream>>>(enc_w2, WencW2, FFc, Dc, flag);
  k_wt<<<dim3(Dc/32, Dc/32, 48), 256, 0, stream>>>(dec_aw, WdecA, Dc, Dc, flag);
  k_wt<<<dim3(FFc/32, Dc/32, 6), 256, 0, stream>>>(dec_w1, WdecW1, Dc, FFc, flag);
  k_wt<<<dim3(Dc/32, FFc/32, 6), 256, 0, stream>>>(dec_w2, WdecW2, FFc, Dc, flag);
  k_cvt<<<32, 256, 0, stream>>>(enc_ab, BencA, 24 * Dc, flag);
  k_cvt<<<32, 256, 0, stream>>>(enc_b1, BencW1, 6 * FFc, flag);
  k_cvt<<<32, 256, 0, stream>>>(enc_b2, BencW2, 6 * Dc, flag);
  k_cvt<<<32, 256, 0, stream>>>(dec_ab, BdecA, 48 * Dc, flag);
  k_cvt<<<32, 256, 0, stream>>>(dec_b1, BdecW1, 6 * FFc, flag);
  k_cvt<<<32, 256, 0, stream>>>(dec_b2, BdecW2, 6 * Dc, flag);

  // ---- helpers (tile shapes chosen for >=1.5 blocks/CU residency) ----
  auto qkv = [&](const u16* A, int M, const u16* Wt, long long wOff,
                 const float* bias, long long bOff, int Lseq) {
    G2 p{}; p.A = A; p.lda = Dc; p.W = Wt + wOff; p.ldw = Dc;
    p.bias = bias; p.bOff = bOff;
    p.C = qbf; p.Ck = kbf; p.Cv = vT; p.vSeg = 2;
    p.Hdim = 1; p.scale = 1.f; p.Lseq = Lseq;
    run_gemm<128, 128, 4>(p, M, 3 * Dc, Dc, 1, stream);   // enc 576 / dec 1152 blocks
  };
  auto kv = [&](const u16* A, int M, const u16* Wt, long long wOff,
                const float* bias, long long bOff, int Lseq) {
    G2 p{}; p.A = A; p.lda = Dc; p.W = Wt + wOff; p.ldw = Dc;
    p.bias = bias; p.bOff = bOff;
    p.C = kbf; p.Ck = vT; p.vSeg = 1;
    p.Hdim = 1; p.scale = 1.f; p.Lseq = Lseq;
    run_gemm<128, 128, 4>(p, M, 2 * Dc, Dc, 1, stream);   // 384 blocks
  };
  auto p768 = [&](const u16* A, int M, const u16* Wt, long long wOff,
                  const float* bias, long long bOff, u16* C, int K, int relu) {
    G2 p{}; p.A = A; p.lda = K; p.W = Wt + wOff; p.ldw = K;
    p.bias = bias; p.bOff = bOff; p.C = C; p.ldc = Dc;
    p.Hdim = 1; p.scale = 1.f; p.relu = relu;
    run_gemm<128, 64, 0>(p, M, Dc, K, 1, stream);         // dec 768 / enc 384 blocks
  };
  auto ffn1 = [&](const u16* A, int M, const u16* Wt, long long wOff,
                  const float* bias, long long bOff) {
    G2 p{}; p.A = A; p.lda = Dc; p.W = Wt + wOff; p.ldw = Dc;
    p.bias = bias; p.bOff = bOff; p.C = ffmid; p.ldc = FFc;
    p.Hdim = 1; p.scale = 1.f; p.relu = 1;
    run_gemm<128, 128, 0>(p, M, FFc, Dc, 1, stream);      // dec 1536 / enc 768 blocks
  };
  auto g_rel = [&]() {
    G2 p{}; p.A = simb; p.lda = LXc; p.sAb = (long long)LXc * LXc;
    p.W = aoT; p.ldw = LXc; p.sWb = (long long)Dc * LXc;
    p.C = ao2; p.ldc = Dc; p.sCb = (long long)LXc * Dc;
    p.Hdim = 1; p.scale = 1.f;
    run_gemm<128, 128, 0>(p, LXc, Dc, LXc, NB, stream);
  };

  // ---- encoder (M = 4096) ----
  for (int i = 0; i < 6; ++i) {
    int M = NB * LYc;
    long long wo = (long long)i * 4 * DD, bo = (long long)i * 4 * Dc;
    qkv(curb_y, M, WencA, wo, BencA, bo, LYc);
    k_attn<0><<<dim3(LYc / 64, NH, NB), 256, 0, stream>>>(qbf, kbf, vT, ao2, LYc, LYc);
    p768(ao2, M, WencA, wo + 3 * DD, BencA, bo + 3 * Dc, deltab, Dc, 0);
    k_lnres3<<<M, 256, 0, stream>>>(curb_y, deltab, enc_lg, (long long)(i*2+0)*Dc, enc_lb, (long long)(i*2+0)*Dc, flag);
    ffn1(curb_y, M, WencW1, (long long)i * DF, BencW1, (long long)i * FFc);
    p768(ffmid, M, WencW2, (long long)i * DF, BencW2, (long long)i * Dc, deltab, FFc, 0);
    k_lnres3<<<M, 256, 0, stream>>>(curb_y, deltab, enc_lg, (long long)(i*2+1)*Dc, enc_lb, (long long)(i*2+1)*Dc, flag);
  }

  // ---- decoder (M = 8192) ----
  for (int i = 0; i < 6; ++i) {
    int M = NB * LXc;
    for (int a = 0; a < 2; ++a) {
      long long wo = (long long)(i * 2 + a) * 4 * DD;
      long long bo = (long long)(i * 2 + a) * 4 * Dc;
      int Lk;
      if (a == 0) {
        qkv(curb_x, M, WdecA, wo, BdecA, bo, LXc);
        Lk = LXc;
      } else {
        p768(curb_x, M, WdecA, wo, BdecA, bo, qbf, Dc, 0);
        kv(curb_y, NB * LYc, WdecA, wo + DD, BdecA, bo + Dc, LYc);
        Lk = LYc;
      }
      k_attn<1><<<dim3(LXc / 64, NH, NB), 256, 0, stream>>>(qbf, kbf, vT, aoT, LXc, Lk);
      g_rel();
      p768(ao2, M, WdecA, wo + 3 * DD, BdecA, bo + 3 * Dc, deltab, Dc, 0);
      k_lnres3<<<M, 256, 0, stream>>>(curb_x, deltab, dec_lg, (long long)(i*3+a)*Dc, dec_lb, (long long)(i*3+a)*Dc, flag);
    }
    ffn1(curb_x, M, WdecW1, (long long)i * DF, BdecW1, (long long)i * FFc);
    p768(ffmid, M, WdecW2, (long long)i * DF, BdecW2, (long long)i * Dc, deltab, FFc, 0);
    k_lnres3<<<M, 256, 0, stream>>>(curb_x, deltab, dec_lg, (long long)(i*3+2)*Dc, dec_lb, (long long)(i*3+2)*Dc, flag);
  }

  k_emit<<<2048, 256, 0, stream>>>(curb_y, curb_x, d_out, flag, NYt, NYt + NXt);
}

// Round 8
// 3167.004 us; speedup vs baseline: 1.5533x; 1.1012x over previous
//
#include <hip/hip_runtime.h>

#define DEV __device__ __forceinline__

constexpr int NB  = 32;
constexpr int LXc = 256;
constexpr int LYc = 128;
constexpr int Dc  = 768;
constexpr int NH  = 12;
constexpr int FFc = 3072;

typedef unsigned short u16;
typedef float f32x4 __attribute__((ext_vector_type(4)));
typedef short s16x8 __attribute__((ext_vector_type(8)));

DEV u16 f2bf(float f) {
  unsigned u = __float_as_uint(f);
  u += 0x7FFFu + ((u >> 16) & 1u);
  return (u16)(u >> 16);
}
DEV float bf2f(u16 w) { return __uint_as_float(((unsigned)w) << 16); }
DEV float ldf(const void* p, long long i, int isbf) {
  return isbf ? bf2f(((const u16*)p)[i]) : ((const float*)p)[i];
}

DEV void gload16(const void* g, void* l) {
  __builtin_amdgcn_global_load_lds(
      (const __attribute__((address_space(1))) void*)g,
      (__attribute__((address_space(3))) void*)l, 16, 0, 0);
}
DEV void barx() {
  asm volatile("" ::: "memory");
  __builtin_amdgcn_s_barrier();
  asm volatile("" ::: "memory");
}

// ---------------- dtype detection ----------------
__global__ void k_detect(const u16* y, int* flag) {
  if (threadIdx.x == 0) {
    int cnt = 0;
    for (int i = 0; i < 256; ++i) {
      u16 w = y[i];
      int e = (w >> 7) & 0xFF;
      if (e == 0 || (e >= 112 && e <= 140)) cnt++;
    }
    *flag = (cnt >= 200) ? 1 : 0;
  }
}

// raw -> bf16 stream
__global__ void k_ingest_b(const void* src, u16* dst, long long n, const int* flag) {
  int isbf = *flag;
  long long i = (long long)blockIdx.x * blockDim.x + threadIdx.x;
  long long st = (long long)gridDim.x * blockDim.x;
  for (; i < n; i += st) dst[i] = isbf ? ((const u16*)src)[i] : f2bf(((const float*)src)[i]);
}

__global__ void k_cvt(const void* src, float* dst, long long n, const int* flag) {
  int isbf = *flag;
  long long i = (long long)blockIdx.x * blockDim.x + threadIdx.x;
  long long st = (long long)gridDim.x * blockDim.x;
  for (; i < n; i += st) dst[i] = ldf(src, i, isbf);
}

__global__ void k_emit(const u16* ybuf, const u16* xbuf, void* out,
                       const int* flag, long long ny, long long nt) {
  int isbf = *flag;
  long long i = (long long)blockIdx.x * blockDim.x + threadIdx.x;
  long long st = (long long)gridDim.x * blockDim.x;
  for (; i < nt; i += st) {
    u16 v = (i < ny) ? ybuf[i] : xbuf[i - ny];
    if (isbf) ((u16*)out)[i] = v;
    else      ((float*)out)[i] = bf2f(v);
  }
}

// ---------------- weight transpose+convert: [R][C] raw -> [C][R] bf16 ----------------
__global__ __launch_bounds__(256) void k_wt(const void* src, u16* dst, int R, int C, const int* flag) {
  int isbf = *flag;
  __shared__ u16 t[32][33];
  long long base = (long long)blockIdx.z * R * C;
  int c0 = blockIdx.x * 32, r0 = blockIdx.y * 32;
  int tx = threadIdx.x & 31, ty = threadIdx.x >> 5;
#pragma unroll
  for (int k = 0; k < 4; ++k) {
    int r = r0 + ty + k * 8;
    t[ty + k * 8][tx] = f2bf(ldf(src, base + (long long)r * C + (c0 + tx), isbf));
  }
  __syncthreads();
#pragma unroll
  for (int k = 0; k < 4; ++k) {
    int c = c0 + ty + k * 8;
    dst[base + (long long)c * R + (r0 + tx)] = t[tx][ty + k * 8];
  }
}

// ---------------- bbox cosine-sim + softmax (bf16 out) ----------------
__global__ __launch_bounds__(256) void k_bboxsim(const void* bbox, const int* flag, u16* sim) {
  int isbf = *flag;
  int b = blockIdx.x >> 8, i = blockIdx.x & 255;
  int j = threadIdx.x;
  long long base = (long long)b * LXc * 4;
  float a[4], c[4];
#pragma unroll
  for (int t = 0; t < 4; ++t) {
    a[t] = ldf(bbox, base + (long long)i * 4 + t, isbf);
    c[t] = ldf(bbox, base + (long long)j * 4 + t, isbf);
  }
  float dot = a[0]*c[0] + a[1]*c[1] + a[2]*c[2] + a[3]*c[3];
  float na  = sqrtf(a[0]*a[0] + a[1]*a[1] + a[2]*a[2] + a[3]*a[3]);
  float ncn = sqrtf(c[0]*c[0] + c[1]*c[1] + c[2]*c[2] + c[3]*c[3]);
  float v = dot / (na * ncn);
  __shared__ float r1[4], r2[4];
  float m = v;
  for (int o = 32; o; o >>= 1) m = fmaxf(m, __shfl_xor(m, o));
  if ((threadIdx.x & 63) == 0) r1[threadIdx.x >> 6] = m;
  __syncthreads();
  m = fmaxf(fmaxf(r1[0], r1[1]), fmaxf(r1[2], r1[3]));
  float e = __expf(v - m);
  float s = e;
  for (int o = 32; o; o >>= 1) s += __shfl_xor(s, o);
  if ((threadIdx.x & 63) == 0) r2[threadIdx.x >> 6] = s;
  __syncthreads();
  s = r2[0] + r2[1] + r2[2] + r2[3];
  sim[((long long)b * LXc + i) * LXc + j] = f2bf(e / s);
}

// ---------------- residual + layernorm, all-bf16 stream (f32 math) ----------------
__global__ __launch_bounds__(256) void k_lnres3(u16* curb, const u16* delta,
                                                const void* g, long long gOff,
                                                const void* bb, long long bOff,
                                                const int* flag) {
  int isbf = *flag;
  long long row = blockIdx.x;
  u16* xr = curb + row * Dc;
  const u16* dr = delta + row * Dc;
  int t = threadIdx.x;
  float v[3];
  float s = 0.f;
#pragma unroll
  for (int i = 0; i < 3; ++i) { int c = t + i * 256; v[i] = bf2f(xr[c]) + bf2f(dr[c]); s += v[i]; }
  __shared__ float r1[4], r2[4];
  for (int o = 32; o; o >>= 1) s += __shfl_xor(s, o);
  if ((t & 63) == 0) r1[t >> 6] = s;
  __syncthreads();
  float mean = (r1[0] + r1[1] + r1[2] + r1[3]) * (1.0f / 768.0f);
  float s2 = 0.f;
#pragma unroll
  for (int i = 0; i < 3; ++i) { float d = v[i] - mean; s2 += d * d; }
  for (int o = 32; o; o >>= 1) s2 += __shfl_xor(s2, o);
  if ((t & 63) == 0) r2[t >> 6] = s2;
  __syncthreads();
  float var = (r2[0] + r2[1] + r2[2] + r2[3]) * (1.0f / 768.0f);
  float rstd = rsqrtf(var + 1e-6f);
#pragma unroll
  for (int i = 0; i < 3; ++i) {
    int c = t + i * 256;
    float o = ldf(g, gOff + c, isbf) * (v[i] - mean) * rstd + ldf(bb, bOff + c, isbf);
    xr[c] = f2bf(o);
  }
}

// ---------------- fused flash attention ----------------
template<int DEC>
__global__ __launch_bounds__(256) void k_attn(const u16* __restrict__ Q,
                                              const u16* __restrict__ Kb,
                                              const u16* __restrict__ Vt,
                                              u16* __restrict__ Out,
                                              int Lq, int Lk) {
  __shared__ __align__(16) u16 Kl[64 * 64];
  __shared__ __align__(16) u16 Vl[64 * 64];
  __shared__ __align__(16) u16 Pl[4][16][72];
  const int tid = threadIdx.x, wid = tid >> 6, lane = tid & 63;
  const int qt = blockIdx.x, h = blockIdx.y, b = blockIdx.z;
  const int q0 = qt * 64 + wid * 16;
  const int rl = lane & 15, sx = lane >> 4;
  const int srow = lane >> 3;
  const int scol8 = ((lane & 7) ^ srow) << 3;

  s16x8 qa[2];
  {
    const u16* qrow = Q + ((long long)b * Lq + q0 + rl) * Dc + h * 64;
    qa[0] = *(const s16x8*)(qrow + sx * 8);
    qa[1] = *(const s16x8*)(qrow + 32 + sx * 8);
  }
  f32x4 o[4] = {};
  float m[4], l[4];
#pragma unroll
  for (int e = 0; e < 4; ++e) { m[e] = -3.0e38f; l[e] = 0.f; }

  const long long kbase = (long long)b * Lk * Dc + h * 64;
  const long long vbase = ((long long)b * Dc + h * 64) * Lk;

  for (int k0 = 0; k0 < Lk; k0 += 64) {
#pragma unroll
    for (int g = 0; g < 2; ++g) {
      int chunk = g * 4 + wid;
      gload16(Kb + kbase + (long long)(k0 + chunk * 8 + srow) * Dc + scol8,
              (char*)Kl + chunk * 1024);
    }
#pragma unroll
    for (int g = 0; g < 2; ++g) {
      int chunk = g * 4 + wid;
      gload16(Vt + vbase + (long long)(chunk * 8 + srow) * Lk + k0 + scol8,
              (char*)Vl + chunk * 1024);
    }
    asm volatile("s_waitcnt vmcnt(0)" ::: "memory");
    barx();

    f32x4 s[4];
#pragma unroll
    for (int n = 0; n < 4; ++n) {
      s16x8 b0 = *(const s16x8*)((char*)Kl + (n * 16 + rl) * 128 + ((sx    ) ^ (rl & 7)) * 16);
      s16x8 b1 = *(const s16x8*)((char*)Kl + (n * 16 + rl) * 128 + ((sx + 4) ^ (rl & 7)) * 16);
      f32x4 acc = {};
      acc = __builtin_amdgcn_mfma_f32_16x16x32_bf16(qa[0], b0, acc, 0, 0, 0);
      acc = __builtin_amdgcn_mfma_f32_16x16x32_bf16(qa[1], b1, acc, 0, 0, 0);
      s[n] = acc;
    }
#pragma unroll
    for (int n = 0; n < 4; ++n)
#pragma unroll
      for (int e = 0; e < 4; ++e) s[n][e] *= 0.125f;

#pragma unroll
    for (int e = 0; e < 4; ++e) {
      float v = fmaxf(fmaxf(s[0][e], s[1][e]), fmaxf(s[2][e], s[3][e]));
      v = fmaxf(v, __shfl_xor(v, 1));
      v = fmaxf(v, __shfl_xor(v, 2));
      v = fmaxf(v, __shfl_xor(v, 4));
      v = fmaxf(v, __shfl_xor(v, 8));
      float mn = fmaxf(m[e], v);
      float alpha = __expf(m[e] - mn);
      m[e] = mn;
      float ls = 0.f;
#pragma unroll
      for (int n = 0; n < 4; ++n) {
        float p = __expf(s[n][e] - mn);
        s[n][e] = p;
        ls += p;
      }
      ls += __shfl_xor(ls, 1);
      ls += __shfl_xor(ls, 2);
      ls += __shfl_xor(ls, 4);
      ls += __shfl_xor(ls, 8);
      l[e] = l[e] * alpha + ls;
#pragma unroll
      for (int n = 0; n < 4; ++n) o[n][e] *= alpha;
    }

#pragma unroll
    for (int e = 0; e < 4; ++e)
#pragma unroll
      for (int n = 0; n < 4; ++n)
        Pl[wid][sx * 4 + e][n * 16 + rl] = f2bf(s[n][e]);
    barx();

    s16x8 pa0 = *(const s16x8*)&Pl[wid][rl][sx * 8];
    s16x8 pa1 = *(const s16x8*)&Pl[wid][rl][32 + sx * 8];
#pragma unroll
    for (int n = 0; n < 4; ++n) {
      s16x8 v0 = *(const s16x8*)((char*)Vl + (n * 16 + rl) * 128 + ((sx    ) ^ (rl & 7)) * 16);
      s16x8 v1 = *(const s16x8*)((char*)Vl + (n * 16 + rl) * 128 + ((sx + 4) ^ (rl & 7)) * 16);
      o[n] = __builtin_amdgcn_mfma_f32_16x16x32_bf16(pa0, v0, o[n], 0, 0, 0);
      o[n] = __builtin_amdgcn_mfma_f32_16x16x32_bf16(pa1, v1, o[n], 0, 0, 0);
    }
    barx();
  }

#pragma unroll
  for (int e = 0; e < 4; ++e) l[e] = 1.0f / l[e];
  if (DEC) {
    u16* Op = Out + ((long long)b * Dc + h * 64) * LXc;
#pragma unroll
    for (int n = 0; n < 4; ++n) {
      union { u16 u[4]; uint2 d; } pk;
#pragma unroll
      for (int e = 0; e < 4; ++e) pk.u[e] = f2bf(o[n][e] * l[e]);
      *(uint2*)&Op[(long long)(n * 16 + rl) * LXc + q0 + sx * 4] = pk.d;
    }
  } else {
    u16* Op = Out + ((long long)b * Lq + q0) * Dc + h * 64;
#pragma unroll
    for (int n = 0; n < 4; ++n)
#pragma unroll
      for (int e = 0; e < 4; ++e)
        Op[(long long)(sx * 4 + e) * Dc + n * 16 + rl] = f2bf(o[n][e] * l[e]);
  }
}

// ---------------- GEMM param block ----------------
struct G2 {
  const u16* A; long long lda, sAb, sAh;
  const u16* W; long long ldw, sWb, sWh;
  const float* bias; long long bOff;
  void* C; long long ldc, sCb, sCh;
  void* Ck; void* Cv; int vSeg;
  int Hdim; float scale; int relu; int Lseq;
};

// ---------------- 128xBN 2-phase MFMA GEMM with T2 LDS swizzle ----------------
// LDS layout: linear dest for global_load_lds; 16B slot s of row r holds global
// slot s ^ (r&7) (inverse-swizzled source). ds_read applies the same XOR.
// MODE 0: bf16 C[row][col], optional relu.  MODE 4: segment-routed QKV.
template<int BM, int BN, int MODE>
__global__ __launch_bounds__(256, 2) void gemm2(G2 p, int M, int N, int K) {
  constexpr int BK = 64;
  __shared__ __align__(16) u16 Al[BM * BK];
  __shared__ __align__(16) u16 Bl[BN * BK];
  const int tid = threadIdx.x, wid = tid >> 6, lane = tid & 63;
  const int z = blockIdx.z, zb = z / p.Hdim, zh = z % p.Hdim;
  int bx = blockIdx.x, by = blockIdx.y;
  if (gridDim.z == 1) {
    int gx = gridDim.x, nwg = gx * gridDim.y;
    int orig = by * gx + bx;
    int q = nwg >> 3, r = nwg & 7, xcd = orig & 7, lin = orig >> 3;
    int wg = (xcd < r ? xcd * (q + 1) : r * (q + 1) + (xcd - r) * q) + lin;
    bx = wg % gx; by = wg / gx;
  }
  const u16* A = p.A + (long long)zb * p.sAb + (long long)zh * p.sAh;
  const u16* W = p.W + (long long)zb * p.sWb + (long long)zh * p.sWh;
  const int m0 = by * BM, n0 = bx * BN;
  const int wr = wid >> 1, wc = wid & 1;
  constexpr int FM = BM / 32, FN = BN / 32;
  f32x4 acc[FM][FN] = {};
  const int lr = lane >> 3;                       // row within 8-row chunk
  const int lo = (((lane & 7) ^ lr) << 3) * 2;    // inverse-swizzled source byte off
  const int rl = lane & 15;
  const int sx = lane >> 4;
  const int slotb0 = (((sx + 0) ^ (rl & 7)) << 4); // swizzled read byte off, ks=0
  const int slotb1 = (((sx + 4) ^ (rl & 7)) << 4); // swizzled read byte off, ks=1

  for (int k0 = 0; k0 < K; k0 += BK) {
#pragma unroll
    for (int i = 0; i < BM / 32; ++i) {
      int chunk = wid * (BM / 32) + i;
      int row = chunk * 8 + lr;
      gload16((const char*)(A + (long long)(m0 + row) * p.lda + k0) + lo,
              (char*)Al + chunk * 1024);
    }
#pragma unroll
    for (int i = 0; i < BN / 32; ++i) {
      int chunk = wid * (BN / 32) + i;
      int row = chunk * 8 + lr;
      gload16((const char*)(W + (long long)(n0 + row) * p.ldw + k0) + lo,
              (char*)Bl + chunk * 1024);
    }
    __syncthreads();
    {
      s16x8 af[FM][2], bfr[FN][2];
#pragma unroll
      for (int i = 0; i < FM; ++i) {
        const char* rbase = (char*)Al + (wr * (BM / 2) + i * 16 + rl) * 128;
        af[i][0] = *(const s16x8*)(rbase + slotb0);
        af[i][1] = *(const s16x8*)(rbase + slotb1);
      }
#pragma unroll
      for (int j = 0; j < FN; ++j) {
        const char* rbase = (char*)Bl + (wc * (BN / 2) + j * 16 + rl) * 128;
        bfr[j][0] = *(const s16x8*)(rbase + slotb0);
        bfr[j][1] = *(const s16x8*)(rbase + slotb1);
      }
#pragma unroll
      for (int ks = 0; ks < 2; ++ks)
#pragma unroll
        for (int i = 0; i < FM; ++i)
#pragma unroll
          for (int j = 0; j < FN; ++j)
            acc[i][j] = __builtin_amdgcn_mfma_f32_16x16x32_bf16(af[i][ks], bfr[j][ks], acc[i][j], 0, 0, 0);
    }
    __syncthreads();
  }

  const int seg = (MODE == 4) ? (n0 / 768) : 0;
#pragma unroll
  for (int j = 0; j < FN; ++j) {
    int col = n0 + wc * (BN / 2) + j * 16 + (lane & 15);
    float bv = p.bias ? p.bias[p.bOff + col] : 0.f;
#pragma unroll
    for (int i = 0; i < FM; ++i) {
      int row0 = m0 + wr * (BM / 2) + i * 16 + (lane >> 4) * 4;
      if (MODE == 0) {
        u16* C = (u16*)p.C + (long long)zb * p.sCb + (long long)zh * p.sCh;
#pragma unroll
        for (int e = 0; e < 4; ++e) {
          float v = acc[i][j][e] * p.scale + bv;
          if (p.relu) v = fmaxf(v, 0.f);
          C[(long long)(row0 + e) * p.ldc + col] = f2bf(v);
        }
      } else {  // MODE 4: segment-routed QKV
        u16* outp = seg == 0 ? (u16*)p.C : (seg == 1 ? (u16*)p.Ck : (u16*)p.Cv);
        int c = col - seg * 768;
        if (seg == p.vSeg) {
          int b = row0 / p.Lseq, l = row0 % p.Lseq;
          union { u16 u[4]; uint2 d; } pk;
#pragma unroll
          for (int e = 0; e < 4; ++e) pk.u[e] = f2bf(acc[i][j][e] + bv);
          *(uint2*)&outp[((long long)b * Dc + c) * p.Lseq + l] = pk.d;
        } else {
#pragma unroll
          for (int e = 0; e < 4; ++e)
            outp[(long long)(row0 + e) * 768 + c] = f2bf(acc[i][j][e] + bv);
        }
      }
    }
  }
}

// ---------------- launch helpers ----------------
template<int BM, int BN, int MODE>
static void run_gemm(const G2& p, int M, int N, int K, int nz, hipStream_t st) {
  dim3 grid(N / BN, M / BM, nz);
  gemm2<BM, BN, MODE><<<grid, 256, 0, st>>>(p, M, N, K);
}

extern "C" void kernel_launch(void* const* d_in, const int* in_sizes, int n_in,
                              void* d_out, int out_size, void* d_ws, size_t ws_size,
                              hipStream_t stream) {
  const void* y_in  = d_in[0];
  const void* x_in  = d_in[1];
  const void* bbox  = d_in[5];
  const void* enc_aw = d_in[6];  const void* enc_ab = d_in[7];
  const void* enc_w1 = d_in[8];  const void* enc_b1 = d_in[9];
  const void* enc_w2 = d_in[10]; const void* enc_b2 = d_in[11];
  const void* enc_lg = d_in[12]; const void* enc_lb = d_in[13];
  const void* dec_aw = d_in[14]; const void* dec_ab = d_in[15];
  const void* dec_w1 = d_in[16]; const void* dec_b1 = d_in[17];
  const void* dec_w2 = d_in[18]; const void* dec_b2 = d_in[19];
  const void* dec_lg = d_in[20]; const void* dec_lb = d_in[21];

  char* base = (char*)d_ws;
  size_t off = 0;
  auto alloc = [&](size_t bytes) { void* p = base + off; off = (off + bytes + 255) & ~(size_t)255; return p; };
  int*  flag = (int*)alloc(256);
  const long long DD = (long long)Dc * Dc;
  const long long DF = (long long)Dc * FFc;
  u16* WencA  = (u16*)alloc(24 * DD * 2);
  u16* WencW1 = (u16*)alloc(6 * DF * 2);
  u16* WencW2 = (u16*)alloc(6 * DF * 2);
  u16* WdecA  = (u16*)alloc(48 * DD * 2);
  u16* WdecW1 = (u16*)alloc(6 * DF * 2);
  u16* WdecW2 = (u16*)alloc(6 * DF * 2);
  float* BencA  = (float*)alloc(24 * Dc * 4);
  float* BencW1 = (float*)alloc(6 * FFc * 4);
  float* BencW2 = (float*)alloc(6 * Dc * 4);
  float* BdecA  = (float*)alloc(48 * Dc * 4);
  float* BdecW1 = (float*)alloc(6 * FFc * 4);
  float* BdecW2 = (float*)alloc(6 * Dc * 4);
  const long long NYt = (long long)NB * LYc * Dc;
  const long long NXt = (long long)NB * LXc * Dc;
  u16*   curb_y = (u16*)alloc(NYt * 2);
  u16*   curb_x = (u16*)alloc(NXt * 2);
  u16*   simb   = (u16*)alloc((long long)NB * LXc * LXc * 2);
  u16*   qbf    = (u16*)alloc(NXt * 2);
  u16*   kbf    = (u16*)alloc(NXt * 2);
  u16*   vT     = (u16*)alloc(NXt * 2);
  u16*   deltab = (u16*)alloc(NXt * 2);
  u16*   aoT    = (u16*)alloc(NXt * 2);
  u16*   ao2    = (u16*)alloc(NXt * 2);
  u16*   ffmid  = (u16*)alloc((long long)NB * LXc * FFc * 2);

  k_detect<<<1, 64, 0, stream>>>((const u16*)y_in, flag);
  k_ingest_b<<<1024, 256, 0, stream>>>(y_in, curb_y, NYt, flag);
  k_ingest_b<<<1024, 256, 0, stream>>>(x_in, curb_x, NXt, flag);
  k_bboxsim<<<NB * LXc, 256, 0, stream>>>(bbox, flag, simb);
  k_wt<<<dim3(Dc/32, Dc/32, 24), 256, 0, stream>>>(enc_aw, WencA, Dc, Dc, flag);
  k_wt<<<dim3(FFc/32, Dc/32, 6), 256, 0, stream>>>(enc_w1, WencW1, Dc, FFc, flag);
  k_wt<<<dim3(Dc/32, FFc/32, 6), 256, 0, stream>>>(enc_w2, WencW2, FFc, Dc, flag);
  k_wt<<<dim3(Dc/32, Dc/32, 48), 256, 0, stream>>>(dec_aw, WdecA, Dc, Dc, flag);
  k_wt<<<dim3(FFc/32, Dc/32, 6), 256, 0, stream>>>(dec_w1, WdecW1, Dc, FFc, flag);
  k_wt<<<dim3(Dc/32, FFc/32, 6), 256, 0, stream>>>(dec_w2, WdecW2, FFc, Dc, flag);
  k_cvt<<<32, 256, 0, stream>>>(enc_ab, BencA, 24 * Dc, flag);
  k_cvt<<<32, 256, 0, stream>>>(enc_b1, BencW1, 6 * FFc, flag);
  k_cvt<<<32, 256, 0, stream>>>(enc_b2, BencW2, 6 * Dc, flag);
  k_cvt<<<32, 256, 0, stream>>>(dec_ab, BdecA, 48 * Dc, flag);
  k_cvt<<<32, 256, 0, stream>>>(dec_b1, BdecW1, 6 * FFc, flag);
  k_cvt<<<32, 256, 0, stream>>>(dec_b2, BdecW2, 6 * Dc, flag);

  // ---- helpers ----
  auto qkv = [&](const u16* A, int M, const u16* Wt, long long wOff,
                 const float* bias, long long bOff, int Lseq) {
    G2 p{}; p.A = A; p.lda = Dc; p.W = Wt + wOff; p.ldw = Dc;
    p.bias = bias; p.bOff = bOff;
    p.C = qbf; p.Ck = kbf; p.Cv = vT; p.vSeg = 2;
    p.Hdim = 1; p.scale = 1.f; p.Lseq = Lseq;
    run_gemm<128, 128, 4>(p, M, 3 * Dc, Dc, 1, stream);
  };
  auto kv = [&](const u16* A, int M, const u16* Wt, long long wOff,
                const float* bias, long long bOff, int Lseq) {
    G2 p{}; p.A = A; p.lda = Dc; p.W = Wt + wOff; p.ldw = Dc;
    p.bias = bias; p.bOff = bOff;
    p.C = kbf; p.Ck = vT; p.vSeg = 1;
    p.Hdim = 1; p.scale = 1.f; p.Lseq = Lseq;
    run_gemm<128, 128, 4>(p, M, 2 * Dc, Dc, 1, stream);
  };
  auto p768 = [&](const u16* A, int M, const u16* Wt, long long wOff,
                  const float* bias, long long bOff, u16* C, int K, int relu) {
    G2 p{}; p.A = A; p.lda = K; p.W = Wt + wOff; p.ldw = K;
    p.bias = bias; p.bOff = bOff; p.C = C; p.ldc = Dc;
    p.Hdim = 1; p.scale = 1.f; p.relu = relu;
    run_gemm<128, 64, 0>(p, M, Dc, K, 1, stream);
  };
  auto ffn1 = [&](const u16* A, int M, const u16* Wt, long long wOff,
                  const float* bias, long long bOff) {
    G2 p{}; p.A = A; p.lda = Dc; p.W = Wt + wOff; p.ldw = Dc;
    p.bias = bias; p.bOff = bOff; p.C = ffmid; p.ldc = FFc;
    p.Hdim = 1; p.scale = 1.f; p.relu = 1;
    run_gemm<128, 128, 0>(p, M, FFc, Dc, 1, stream);
  };
  auto g_rel = [&]() {
    G2 p{}; p.A = simb; p.lda = LXc; p.sAb = (long long)LXc * LXc;
    p.W = aoT; p.ldw = LXc; p.sWb = (long long)Dc * LXc;
    p.C = ao2; p.ldc = Dc; p.sCb = (long long)LXc * Dc;
    p.Hdim = 1; p.scale = 1.f;
    run_gemm<128, 128, 0>(p, LXc, Dc, LXc, NB, stream);
  };

  // ---- encoder (M = 4096) ----
  for (int i = 0; i < 6; ++i) {
    int M = NB * LYc;
    long long wo = (long long)i * 4 * DD, bo = (long long)i * 4 * Dc;
    qkv(curb_y, M, WencA, wo, BencA, bo, LYc);
    k_attn<0><<<dim3(LYc / 64, NH, NB), 256, 0, stream>>>(qbf, kbf, vT, ao2, LYc, LYc);
    p768(ao2, M, WencA, wo + 3 * DD, BencA, bo + 3 * Dc, deltab, Dc, 0);
    k_lnres3<<<M, 256, 0, stream>>>(curb_y, deltab, enc_lg, (long long)(i*2+0)*Dc, enc_lb, (long long)(i*2+0)*Dc, flag);
    ffn1(curb_y, M, WencW1, (long long)i * DF, BencW1, (long long)i * FFc);
    p768(ffmid, M, WencW2, (long long)i * DF, BencW2, (long long)i * Dc, deltab, FFc, 0);
    k_lnres3<<<M, 256, 0, stream>>>(curb_y, deltab, enc_lg, (long long)(i*2+1)*Dc, enc_lb, (long long)(i*2+1)*Dc, flag);
  }

  // ---- decoder (M = 8192) ----
  for (int i = 0; i < 6; ++i) {
    int M = NB * LXc;
    for (int a = 0; a < 2; ++a) {
      long long wo = (long long)(i * 2 + a) * 4 * DD;
      long long bo = (long long)(i * 2 + a) * 4 * Dc;
      int Lk;
      if (a == 0) {
        qkv(curb_x, M, WdecA, wo, BdecA, bo, LXc);
        Lk = LXc;
      } else {
        p768(curb_x, M, WdecA, wo, BdecA, bo, qbf, Dc, 0);
        kv(curb_y, NB * LYc, WdecA, wo + DD, BdecA, bo + Dc, LYc);
        Lk = LYc;
      }
      k_attn<1><<<dim3(LXc / 64, NH, NB), 256, 0, stream>>>(qbf, kbf, vT, aoT, LXc, Lk);
      g_rel();
      p768(ao2, M, WdecA, wo + 3 * DD, BdecA, bo + 3 * Dc, deltab, Dc, 0);
      k_lnres3<<<M, 256, 0, stream>>>(curb_x, deltab, dec_lg, (long long)(i*3+a)*Dc, dec_lb, (long long)(i*3+a)*Dc, flag);
    }
    ffn1(curb_x, M, WdecW1, (long long)i * DF, BdecW1, (long long)i * FFc);
    p768(ffmid, M, WdecW2, (long long)i * DF, BdecW2, (long long)i * Dc, deltab, FFc, 0);
    k_lnres3<<<M, 256, 0, stream>>>(curb_x, deltab, dec_lg, (long long)(i*3+2)*Dc, dec_lb, (long long)(i*3+2)*Dc, flag);
  }

  k_emit<<<2048, 256, 0, stream>>>(curb_y, curb_x, d_out, flag, NYt, NYt + NXt);
}